// Round 6
// baseline (359.224 us; speedup 1.0000x reference)
//
#include <hip/hip_runtime.h>
#include <hip/hip_bf16.h>
#include <float.h>

using bf16 = __hip_bfloat16;
typedef __attribute__((ext_vector_type(8))) short bf16x8;
typedef __attribute__((ext_vector_type(4))) float f32x4;
typedef __attribute__((ext_vector_type(16))) float f32x16;

#define DIM   1024
#define NSEQ  4096
#define BATCH 2
#define NH    16
#define HD    64
#define NSEG  8
#define MSEG  512
#define ROWS  (BATCH*NSEQ)   // 8192
#define NC    (BATCH*NH)     // 32

__device__ __forceinline__ void gload16(const bf16* g, bf16* l) {
    __builtin_amdgcn_global_load_lds((const __attribute__((address_space(1))) unsigned int*)g,
                                     (__attribute__((address_space(3))) unsigned int*)l, 16, 0, 0);
}

// ---------------------------------------------------------------- rope table
__global__ void k_rope_tab(float* __restrict__ cosT, float* __restrict__ sinT) {
    int idx = blockIdx.x * 256 + threadIdx.x;     // 4096*32 = 131072
    int t = idx >> 5, i = idx & 31;
    float freq = 1.0f / powf(10000.0f, (float)(2 * i) * (1.0f / 64.0f));
    float a = (float)t * freq;
    cosT[idx] = cosf(a);
    sinT[idx] = sinf(a);
}

// ---------------------------------------------------------------- x -> bf16
__global__ void k_convert_x(const float* __restrict__ X, bf16* __restrict__ Xb) {
    int i = (blockIdx.x * 256 + threadIdx.x) * 4;
    float4 v = *(const float4*)&X[i];
    union { bf16 h[4]; uint2 u; } p;
    p.h[0] = __float2bfloat16(v.x);
    p.h[1] = __float2bfloat16(v.y);
    p.h[2] = __float2bfloat16(v.z);
    p.h[3] = __float2bfloat16(v.w);
    *(uint2*)&Xb[i] = p.u;
}

// ------------------------------------------- W[k][n] -> Wt[n][k] (bf16)
__global__ void k_transpose(const float* __restrict__ W, bf16* __restrict__ Wt) {
    __shared__ float tile[32][33];
    int bx = blockIdx.x * 32;   // n
    int by = blockIdx.y * 32;   // k
    int tx = threadIdx.x;
    for (int i = threadIdx.y; i < 32; i += 8)
        tile[i][tx] = W[(size_t)(by + i) * DIM + bx + tx];
    __syncthreads();
    for (int i = threadIdx.y; i < 32; i += 8)
        Wt[(size_t)(bx + i) * DIM + by + tx] = __float2bfloat16(tile[tx][i]);
}

// ------------------------------------- merged Q+KV projection GEMM, 2-phase dbuf
__launch_bounds__(256, 4)
__global__ void k_gemm_qkv(const bf16* __restrict__ A, const bf16* __restrict__ Bq,
                           const bf16* __restrict__ Bkv, bf16* __restrict__ Yq,
                           bf16* __restrict__ Ykv) {
    __shared__ alignas(16) bf16 As[2][128 * 32];
    __shared__ alignas(16) bf16 Bs[2][128 * 32];
    const int K = DIM;
    int tid = threadIdx.x;
    int lane = tid & 63, wave = tid >> 6;
    int wr = (wave >> 1) * 64, wc = (wave & 1) * 64;
    int id = blockIdx.x;
    int xcd = id & 7, rank = id >> 3;      // rank 0..127
    int by = xcd * 8 + (rank >> 4);        // 0..63
    int bxx = rank & 15;                   // 0..15 (virtual n block)
    int m0 = by * 128;
    const bf16* Bt = (bxx < 8) ? Bq : Bkv;
    bf16* C = (bxx < 8) ? Yq : Ykv;
    int n0 = (bxx & 7) * 128;
    int row = lane & 15, kk = (lane >> 4) * 8;
    int ch0 = wave * 128 + lane, ch1 = ch0 + 64;
    int r0 = ch0 >> 2, c0e = (ch0 & 3) * 8;
    int r1 = ch1 >> 2, c1e = (ch1 & 3) * 8;
    f32x4 acc[4][4] = {};
    gload16(&A[(size_t)(m0 + r0) * K + c0e], &As[0][wave * 1024]);
    gload16(&A[(size_t)(m0 + r1) * K + c1e], &As[0][wave * 1024 + 512]);
    gload16(&Bt[(size_t)(n0 + r0) * K + c0e], &Bs[0][wave * 1024]);
    gload16(&Bt[(size_t)(n0 + r1) * K + c1e], &Bs[0][wave * 1024 + 512]);
    __syncthreads();
    int cur = 0;
    for (int k0 = 0; k0 < K; k0 += 32) {
        int nxt = cur ^ 1;
        if (k0 + 32 < K) {
            gload16(&A[(size_t)(m0 + r0) * K + k0 + 32 + c0e], &As[nxt][wave * 1024]);
            gload16(&A[(size_t)(m0 + r1) * K + k0 + 32 + c1e], &As[nxt][wave * 1024 + 512]);
            gload16(&Bt[(size_t)(n0 + r0) * K + k0 + 32 + c0e], &Bs[nxt][wave * 1024]);
            gload16(&Bt[(size_t)(n0 + r1) * K + k0 + 32 + c1e], &Bs[nxt][wave * 1024 + 512]);
        }
        bf16x8 af[4], bfr[4];
#pragma unroll
        for (int mt = 0; mt < 4; ++mt) af[mt] = *(const bf16x8*)&As[cur][(wr + mt * 16 + row) * 32 + kk];
#pragma unroll
        for (int nt = 0; nt < 4; ++nt) bfr[nt] = *(const bf16x8*)&Bs[cur][(wc + nt * 16 + row) * 32 + kk];
#pragma unroll
        for (int mt = 0; mt < 4; ++mt)
#pragma unroll
            for (int nt = 0; nt < 4; ++nt)
                acc[mt][nt] = __builtin_amdgcn_mfma_f32_16x16x32_bf16(af[mt], bfr[nt], acc[mt][nt], 0, 0, 0);
        __syncthreads();
        cur = nxt;
    }
    int orow = (lane >> 4) * 4, ocol = lane & 15;
#pragma unroll
    for (int mt = 0; mt < 4; ++mt)
#pragma unroll
        for (int nt = 0; nt < 4; ++nt)
#pragma unroll
            for (int i = 0; i < 4; ++i)
                C[(size_t)(m0 + wr + mt * 16 + orow + i) * DIM + n0 + wc + nt * 16 + ocol] =
                    __float2bfloat16(acc[mt][nt][i]);
}

// final GEMM: 2-phase dbuf, XCD swizzle, per-row-tile weight/bias select, fp32 out
__launch_bounds__(256, 2)
__global__ void k_gemm_out(const bf16* __restrict__ A, const bf16* __restrict__ Bt0,
                           const bf16* __restrict__ Bt1, const float* __restrict__ bias0,
                           const float* __restrict__ bias1, float* __restrict__ C) {
    __shared__ alignas(16) bf16 As[2][128 * 32];
    __shared__ alignas(16) bf16 Bs[2][128 * 32];
    const int K = DIM;
    int tid = threadIdx.x;
    int lane = tid & 63, wave = tid >> 6;
    int wr = (wave >> 1) * 64, wc = (wave & 1) * 64;
    int id = blockIdx.x;                   // 512 blocks
    int xcd = id & 7, rank = id >> 3;      // 0..63
    int by = xcd * 8 + (rank >> 3);        // 0..63
    int bx = rank & 7;
    int m0 = by * 128, n0 = bx * 128;
    bool first = (m0 & (NSEQ - 1)) < MSEG;
    const bf16* Bt = first ? Bt0 : Bt1;
    const float* bias = first ? bias0 : bias1;
    int row = lane & 15, kk = (lane >> 4) * 8;
    int ch0 = wave * 128 + lane, ch1 = ch0 + 64;
    int r0 = ch0 >> 2, c0e = (ch0 & 3) * 8;
    int r1 = ch1 >> 2, c1e = (ch1 & 3) * 8;
    f32x4 acc[4][4] = {};
    gload16(&A[(size_t)(m0 + r0) * K + c0e], &As[0][wave * 1024]);
    gload16(&A[(size_t)(m0 + r1) * K + c1e], &As[0][wave * 1024 + 512]);
    gload16(&Bt[(size_t)(n0 + r0) * K + c0e], &Bs[0][wave * 1024]);
    gload16(&Bt[(size_t)(n0 + r1) * K + c1e], &Bs[0][wave * 1024 + 512]);
    __syncthreads();
    int cur = 0;
    for (int k0 = 0; k0 < K; k0 += 32) {
        int nxt = cur ^ 1;
        if (k0 + 32 < K) {
            gload16(&A[(size_t)(m0 + r0) * K + k0 + 32 + c0e], &As[nxt][wave * 1024]);
            gload16(&A[(size_t)(m0 + r1) * K + k0 + 32 + c1e], &As[nxt][wave * 1024 + 512]);
            gload16(&Bt[(size_t)(n0 + r0) * K + k0 + 32 + c0e], &Bs[nxt][wave * 1024]);
            gload16(&Bt[(size_t)(n0 + r1) * K + k0 + 32 + c1e], &Bs[nxt][wave * 1024 + 512]);
        }
        bf16x8 af[4], bfr[4];
#pragma unroll
        for (int mt = 0; mt < 4; ++mt) af[mt] = *(const bf16x8*)&As[cur][(wr + mt * 16 + row) * 32 + kk];
#pragma unroll
        for (int nt = 0; nt < 4; ++nt) bfr[nt] = *(const bf16x8*)&Bs[cur][(wc + nt * 16 + row) * 32 + kk];
#pragma unroll
        for (int mt = 0; mt < 4; ++mt)
#pragma unroll
            for (int nt = 0; nt < 4; ++nt)
                acc[mt][nt] = __builtin_amdgcn_mfma_f32_16x16x32_bf16(af[mt], bfr[nt], acc[mt][nt], 0, 0, 0);
        __syncthreads();
        cur = nxt;
    }
    int orow = (lane >> 4) * 4, ocol = lane & 15;
#pragma unroll
    for (int mt = 0; mt < 4; ++mt)
#pragma unroll
        for (int nt = 0; nt < 4; ++nt) {
            float bv = bias[n0 + wc + nt * 16 + ocol];
#pragma unroll
            for (int i = 0; i < 4; ++i)
                C[(size_t)(m0 + wr + mt * 16 + orow + i) * DIM + n0 + wc + nt * 16 + ocol] = acc[mt][nt][i] + bv;
        }
}

// ---------------------------------------------------------------- RoPE (Q) from bf16 Y
__global__ void k_rope_q(const bf16* __restrict__ Y, const float* __restrict__ cosT,
                         const float* __restrict__ sinT, bf16* __restrict__ Qb) {
    int idx = blockIdx.x * 256 + threadIdx.x;   // ROWS*DIM/2 threads
    int e = idx & 31;
    int head = (idx >> 5) & 15;
    int rowg = idx >> 9;                        // 0..8191
    int t = rowg & (NSEQ - 1), bidx = rowg >> 12;
    float x1 = __bfloat162float(Y[(size_t)rowg * DIM + head * HD + e]);
    float x2 = __bfloat162float(Y[(size_t)rowg * DIM + head * HD + e + 32]);
    float cv = cosT[t * 32 + e], sv = sinT[t * 32 + e];
    float o1 = (x1 * cv - x2 * sv) * 0.125f;    // * d^-0.5
    float o2 = (x2 * cv + x1 * sv) * 0.125f;
    int c = bidx * NH + head;
    size_t base = ((size_t)c * NSEQ + t) * HD;
    Qb[base + e]      = __float2bfloat16(o1);
    Qb[base + e + 32] = __float2bfloat16(o2);
}

// --------------------------- RoPE (KV) + LDS-tiled transpose (coalesced KVt writes)
__global__ void k_rope_kv(const bf16* __restrict__ Y, const float* __restrict__ cosT,
                          const float* __restrict__ sinT, bf16* __restrict__ KVb,
                          bf16* __restrict__ KVt) {
    __shared__ bf16 T[64][264];
    int c = blockIdx.y, tt = blockIdx.x;
    int bidx = c >> 4, head = c & 15;
    int t0 = tt * 256;
    int e = threadIdx.x & 31;        // 0..31
    int tl = threadIdx.x >> 5;       // 0..7
    for (int it = 0; it < 32; ++it) {
        int tloc = it * 8 + tl;
        int t = t0 + tloc;
        int rowg = bidx * NSEQ + t;
        float x1 = __bfloat162float(Y[(size_t)rowg * DIM + head * HD + e]);
        float x2 = __bfloat162float(Y[(size_t)rowg * DIM + head * HD + e + 32]);
        float cv = cosT[t * 32 + e], sv = sinT[t * 32 + e];
        bf16 b1 = __float2bfloat16(x1 * cv - x2 * sv);
        bf16 b2 = __float2bfloat16(x2 * cv + x1 * sv);
        size_t base = ((size_t)c * NSEQ + t) * HD;
        KVb[base + e]      = b1;
        KVb[base + e + 32] = b2;
        T[e][tloc]      = b1;
        T[e + 32][tloc] = b2;
    }
    __syncthreads();
    int d = threadIdx.x >> 2, part = threadIdx.x & 3;
    size_t trow = ((size_t)c * HD + d) * NSEQ + t0;
#pragma unroll
    for (int k = 0; k < 8; ++k) {
        int col = k * 32 + part * 8;
        union { bf16 h[8]; uint4 u; } pk;
#pragma unroll
        for (int j = 0; j < 8; ++j) pk.h[j] = T[d][col + j];
        *(uint4*)&KVt[trow + col] = pk.u;
    }
}

// ---------------------------------------------------------------- attention (swapped-QK 32x32)
// In-block KV-split: block = 32 q-rows, its 4 waves split the kv range; LDS merge.
// grid 4096 = 8 XCDs x 4 channels x 128 (seg,qb) heavy-first
__launch_bounds__(256, 6)
__global__ void k_attn(const bf16* __restrict__ Qb, const bf16* __restrict__ KVb,
                       const bf16* __restrict__ KVt, bf16* __restrict__ Ob) {
    __shared__ float Osh[32][68];
    __shared__ float Msh[4][32];
    __shared__ float Lsh[4][32];
    int lane = threadIdx.x & 63, wave = threadIdx.x >> 6;
    int hi = lane >> 5, lq = lane & 31;
    int id = blockIdx.x;
    int xcd = id & 7, rank = id >> 3;           // rank 0..511
    int c = xcd * 4 + (rank & 3);
    int hr = rank >> 2;                         // 0..127, heavy-first
    int seg, qb;
    if (hr < 112) { qb = 15 - hr / 7; seg = 1 + hr % 7; }
    else          { seg = 0; qb = 127 - hr; }
    int i0 = qb * 32;                           // q-row offset within segment
    int bidx = c >> 4, head = c & 15;
    int tq = seg * MSEG + i0 + lq;
    const bf16* qptr = &Qb[((size_t)c * NSEQ + tq) * HD + hi * 8];
    bf16x8 qf[4];
#pragma unroll
    for (int dc = 0; dc < 4; ++dc) qf[dc] = *(const bf16x8*)&qptr[dc * 16];
    f32x16 o0 = {}, o1 = {};
    float mrun = -1e30f, lrun = 0.f;            // finite sentinel (see masked-row note)
    int kvbase = (seg == 0) ? 0 : (seg - 1) * MSEG;
    int cstart = (seg == 0) ? 0 : MSEG;
    int nIt = (cstart + i0 + 32) >> 5;          // 32-kv tiles total
    // wave's contiguous chunk of tiles
    int bq = nIt >> 2, rem = nIt & 3;
    int nw = bq + (wave < rem ? 1 : 0);
    int sw = wave * bq + (wave < rem ? wave : rem);

    const bf16* kbase = &KVb[((size_t)c * NSEQ + kvbase + lq) * HD + hi * 8];
    const bf16* vbase = &KVt[((size_t)c * HD + lq) * NSEQ + kvbase + hi * 8];

    for (int it = sw; it < sw + nw; ++it) {
        int c0 = it * 32;
        const bf16* kp = kbase + (size_t)c0 * HD;
        const bf16* vp = vbase + c0;
        bf16x8 kf0 = *(const bf16x8*)&kp[0];
        bf16x8 kf1 = *(const bf16x8*)&kp[16];
        bf16x8 kf2 = *(const bf16x8*)&kp[32];
        bf16x8 kf3 = *(const bf16x8*)&kp[48];
        bf16x8 vf0 = *(const bf16x8*)&vp[0];
        bf16x8 vf1 = *(const bf16x8*)&vp[16];
        bf16x8 vf2 = *(const bf16x8*)&vp[(size_t)32 * NSEQ];
        bf16x8 vf3 = *(const bf16x8*)&vp[(size_t)32 * NSEQ + 16];
        f32x16 s = {};
        __builtin_amdgcn_s_setprio(1);
        s = __builtin_amdgcn_mfma_f32_32x32x16_bf16(kf0, qf[0], s, 0, 0, 0);
        s = __builtin_amdgcn_mfma_f32_32x32x16_bf16(kf1, qf[1], s, 0, 0, 0);
        s = __builtin_amdgcn_mfma_f32_32x32x16_bf16(kf2, qf[2], s, 0, 0, 0);
        s = __builtin_amdgcn_mfma_f32_32x32x16_bf16(kf3, qf[3], s, 0, 0, 0);
        __builtin_amdgcn_s_setprio(0);
        if (c0 + 31 >= cstart && c0 + 31 - cstart > i0) {
#pragma unroll
            for (int r = 0; r < 16; ++r) {
                int kvg = c0 + ((r & 3) + 8 * (r >> 2) + 4 * hi);
                if (kvg >= cstart && kvg - cstart > i0 + lq) s[r] = -FLT_MAX;
            }
        }
        // online softmax, defer-max
        float m8[8], m4[4];
#pragma unroll
        for (int r = 0; r < 8; ++r) m8[r] = fmaxf(s[2 * r], s[2 * r + 1]);
#pragma unroll
        for (int r = 0; r < 4; ++r) m4[r] = fmaxf(m8[2 * r], m8[2 * r + 1]);
        float vmax = fmaxf(fmaxf(m4[0], m4[1]), fmaxf(m4[2], m4[3]));
        vmax = fmaxf(vmax, __shfl_xor(vmax, 32));
        if (__any(vmax > mrun + 8.0f)) {
            float nm = fmaxf(mrun, vmax);
            float al = __expf(mrun - nm);
#pragma unroll
            for (int r = 0; r < 16; ++r) { o0[r] *= al; o1[r] *= al; }
            lrun *= al;
            mrun = nm;
        }
        float p[16];
#pragma unroll
        for (int r = 0; r < 16; ++r) p[r] = __expf(s[r] - mrun);
        float a8[8], a4[4];
#pragma unroll
        for (int r = 0; r < 8; ++r) a8[r] = p[2 * r] + p[2 * r + 1];
#pragma unroll
        for (int r = 0; r < 4; ++r) a4[r] = a8[2 * r] + a8[2 * r + 1];
        lrun += (a4[0] + a4[1]) + (a4[2] + a4[3]);
        // P^T -> B-fragment (pack + half-exchange, 4 shfl)
        unsigned pk[8];
#pragma unroll
        for (int k = 0; k < 8; ++k) {
            union { bf16 h[2]; unsigned u; } cv;
            cv.h[0] = __float2bfloat16(p[2 * k]);
            cv.h[1] = __float2bfloat16(p[2 * k + 1]);
            pk[k] = cv.u;
        }
        unsigned u0 = hi ? pk[0] : pk[2];
        unsigned u1 = hi ? pk[1] : pk[3];
        unsigned u2 = hi ? pk[4] : pk[6];
        unsigned u3 = hi ? pk[5] : pk[7];
        unsigned w0 = (unsigned)__shfl_xor((int)u0, 32);
        unsigned w1 = (unsigned)__shfl_xor((int)u1, 32);
        unsigned w2 = (unsigned)__shfl_xor((int)u2, 32);
        unsigned w3 = (unsigned)__shfl_xor((int)u3, 32);
        union { unsigned u[4]; bf16x8 v; } b0, b1;
        if (hi == 0) {
            b0.u[0] = pk[0]; b0.u[1] = pk[1]; b0.u[2] = w0; b0.u[3] = w1;
            b1.u[0] = pk[4]; b1.u[1] = pk[5]; b1.u[2] = w2; b1.u[3] = w3;
        } else {
            b0.u[0] = w0; b0.u[1] = w1; b0.u[2] = pk[2]; b0.u[3] = pk[3];
            b1.u[0] = w2; b1.u[1] = w3; b1.u[2] = pk[6]; b1.u[3] = pk[7];
        }
        __builtin_amdgcn_s_setprio(1);
        o0 = __builtin_amdgcn_mfma_f32_32x32x16_bf16(vf0, b0.v, o0, 0, 0, 0);
        o1 = __builtin_amdgcn_mfma_f32_32x32x16_bf16(vf2, b0.v, o1, 0, 0, 0);
        o0 = __builtin_amdgcn_mfma_f32_32x32x16_bf16(vf1, b1.v, o0, 0, 0, 0);
        o1 = __builtin_amdgcn_mfma_f32_32x32x16_bf16(vf3, b1.v, o1, 0, 0, 0);
        __builtin_amdgcn_s_setprio(0);
    }
    // ---- in-block merge of 4 kv-split partials
    lrun += __shfl_xor(lrun, 32);
    if (lane < 32) { Msh[wave][lq] = mrun; Lsh[wave][lq] = lrun; }
    __syncthreads();
    float M = fmaxf(fmaxf(Msh[0][lq], Msh[1][lq]), fmaxf(Msh[2][lq], Msh[3][lq]));
    float myscale = __expf(mrun - M);
#pragma unroll
    for (int r = 0; r < 16; ++r) { o0[r] *= myscale; o1[r] *= myscale; }
    // sequential accumulate into Osh
#pragma unroll
    for (int w = 0; w < 4; ++w) {
        if (wave == w) {
#pragma unroll
            for (int a = 0; a < 4; ++a) {
                float4* d0p = (float4*)&Osh[lq][8 * a + 4 * hi];
                float4* d1p = (float4*)&Osh[lq][32 + 8 * a + 4 * hi];
                float4 v0 = make_float4(o0[4 * a], o0[4 * a + 1], o0[4 * a + 2], o0[4 * a + 3]);
                float4 v1 = make_float4(o1[4 * a], o1[4 * a + 1], o1[4 * a + 2], o1[4 * a + 3]);
                if (w == 0) { *d0p = v0; *d1p = v1; }
                else {
                    float4 c0v = *d0p, c1v = *d1p;
                    c0v.x += v0.x; c0v.y += v0.y; c0v.z += v0.z; c0v.w += v0.w;
                    c1v.x += v1.x; c1v.y += v1.y; c1v.z += v1.z; c1v.w += v1.w;
                    *d0p = c0v; *d1p = c1v;
                }
            }
        }
        __syncthreads();
    }
    // ---- normalize + output: thread -> (q, 8-wide d group)
    int q = threadIdx.x >> 3, dg = (threadIdx.x & 7) * 8;
    float lt = Lsh[0][q] * __expf(Msh[0][q] - fmaxf(fmaxf(Msh[0][q], Msh[1][q]), fmaxf(Msh[2][q], Msh[3][q])));
    {
        float Mq = fmaxf(fmaxf(Msh[0][q], Msh[1][q]), fmaxf(Msh[2][q], Msh[3][q]));
        lt = 0.f;
#pragma unroll
        for (int w = 0; w < 4; ++w) lt += Lsh[w][q] * __expf(Msh[w][q] - Mq);
    }
    float inv = 1.0f / lt;
    float4 va = *(float4*)&Osh[q][dg];
    float4 vb = *(float4*)&Osh[q][dg + 4];
    union { bf16 h[8]; uint4 u; } pkd;
    pkd.h[0] = __float2bfloat16(va.x * inv); pkd.h[1] = __float2bfloat16(va.y * inv);
    pkd.h[2] = __float2bfloat16(va.z * inv); pkd.h[3] = __float2bfloat16(va.w * inv);
    pkd.h[4] = __float2bfloat16(vb.x * inv); pkd.h[5] = __float2bfloat16(vb.y * inv);
    pkd.h[6] = __float2bfloat16(vb.z * inv); pkd.h[7] = __float2bfloat16(vb.w * inv);
    int tqo = seg * MSEG + i0 + q;
    *(uint4*)&Ob[((size_t)bidx * NSEQ + tqo) * DIM + head * HD + dg] = pkd.u;
}

// ---------------------------------------------------------------- launch
extern "C" void kernel_launch(void* const* d_in, const int* in_sizes, int n_in,
                              void* d_out, int out_size, void* d_ws, size_t ws_size,
                              hipStream_t stream) {
    const float* x   = (const float*)d_in[0];
    const float* Wq  = (const float*)d_in[1];
    const float* Wkv = (const float*)d_in[2];
    const float* Wo  = (const float*)d_in[3];
    const float* bo  = (const float*)d_in[4];
    const float* Wo0 = (const float*)d_in[5];
    const float* bo0 = (const float*)d_in[6];
    float* out = (float*)d_out;

    char* ws = (char*)d_ws;
    size_t off = 0;
    auto alloc = [&](size_t bytes) { void* p = ws + off; off += (bytes + 255) & ~(size_t)255; return p; };
    float* cosT = (float*)alloc((size_t)NSEQ * 32 * 4);
    float* sinT = (float*)alloc((size_t)NSEQ * 32 * 4);
    bf16* Xb    = (bf16*)alloc((size_t)ROWS * DIM * 2);
    bf16* WqT   = (bf16*)alloc((size_t)DIM * DIM * 2);
    bf16* WkvT  = (bf16*)alloc((size_t)DIM * DIM * 2);
    bf16* WoT   = (bf16*)alloc((size_t)DIM * DIM * 2);
    bf16* Wo0T  = (bf16*)alloc((size_t)DIM * DIM * 2);
    bf16* Yq    = (bf16*)alloc((size_t)ROWS * DIM * 2);
    bf16* Ykv   = (bf16*)alloc((size_t)ROWS * DIM * 2);
    bf16* Qb    = (bf16*)alloc((size_t)NC * NSEQ * HD * 2);
    bf16* KVb   = (bf16*)alloc((size_t)NC * NSEQ * HD * 2);
    bf16* KVt   = (bf16*)alloc((size_t)NC * HD * NSEQ * 2);
    bf16* Ob    = (bf16*)alloc((size_t)ROWS * DIM * 2);

    hipLaunchKernelGGL(k_rope_tab, dim3(NSEQ * 32 / 256), dim3(256), 0, stream, cosT, sinT);
    hipLaunchKernelGGL(k_convert_x, dim3(ROWS * DIM / 4 / 256), dim3(256), 0, stream, x, Xb);
    hipLaunchKernelGGL(k_transpose, dim3(32, 32), dim3(32, 8), 0, stream, Wq, WqT);
    hipLaunchKernelGGL(k_transpose, dim3(32, 32), dim3(32, 8), 0, stream, Wkv, WkvT);
    hipLaunchKernelGGL(k_transpose, dim3(32, 32), dim3(32, 8), 0, stream, Wo, WoT);
    hipLaunchKernelGGL(k_transpose, dim3(32, 32), dim3(32, 8), 0, stream, Wo0, Wo0T);

    hipLaunchKernelGGL(k_gemm_qkv, dim3(1024), dim3(256), 0, stream, Xb, WqT, WkvT, Yq, Ykv);
    hipLaunchKernelGGL(k_rope_q, dim3(ROWS * DIM / 2 / 256), dim3(256), 0, stream, Yq, cosT, sinT, Qb);
    hipLaunchKernelGGL(k_rope_kv, dim3(16, 32), dim3(256), 0, stream, Ykv, cosT, sinT, KVb, KVt);

    hipLaunchKernelGGL(k_attn, dim3(4096), dim3(256), 0, stream, Qb, KVb, KVt, Ob);

    hipLaunchKernelGGL(k_gemm_out, dim3(512), dim3(256), 0, stream, Ob, Wo0T, WoT, bo0, bo, out);
}

// Round 8
// 203.160 us; speedup vs baseline: 1.7682x; 1.7682x over previous
//
#include <hip/hip_runtime.h>
#include <hip/hip_bf16.h>
#include <float.h>

using bf16 = __hip_bfloat16;
typedef __attribute__((ext_vector_type(8))) short bf16x8;
typedef __attribute__((ext_vector_type(4))) float f32x4;
typedef __attribute__((ext_vector_type(16))) float f32x16;

#define DIM   1024
#define NSEQ  4096
#define BATCH 2
#define NH    16
#define HD    64
#define NSEG  8
#define MSEG  512
#define ROWS  (BATCH*NSEQ)   // 8192
#define NC    (BATCH*NH)     // 32
#define QSCALE (0.125f * 1.44269504f)   // d^-0.5 * log2(e)  (exp2 softmax)

__device__ __forceinline__ float fast_exp2(float x) {
    float r;
    asm volatile("v_exp_f32 %0, %1" : "=v"(r) : "v"(x));
    return r;
}

__device__ __forceinline__ void gload16(const bf16* g, bf16* l) {
    __builtin_amdgcn_global_load_lds((const __attribute__((address_space(1))) unsigned int*)g,
                                     (__attribute__((address_space(3))) unsigned int*)l, 16, 0, 0);
}

// ---------------------------------------------------------------- rope table
__global__ void k_rope_tab(float* __restrict__ cosT, float* __restrict__ sinT) {
    int idx = blockIdx.x * 256 + threadIdx.x;     // 4096*32 = 131072
    int t = idx >> 5, i = idx & 31;
    float freq = 1.0f / powf(10000.0f, (float)(2 * i) * (1.0f / 64.0f));
    float a = (float)t * freq;
    cosT[idx] = cosf(a);
    sinT[idx] = sinf(a);
}

// ---------------------------------------------------------------- x -> bf16
__global__ void k_convert_x(const float* __restrict__ X, bf16* __restrict__ Xb) {
    int i = (blockIdx.x * 256 + threadIdx.x) * 4;
    float4 v = *(const float4*)&X[i];
    union { bf16 h[4]; uint2 u; } p;
    p.h[0] = __float2bfloat16(v.x);
    p.h[1] = __float2bfloat16(v.y);
    p.h[2] = __float2bfloat16(v.z);
    p.h[3] = __float2bfloat16(v.w);
    *(uint2*)&Xb[i] = p.u;
}

// ------------------------------------------- W[k][n] -> Wt[n][k] (bf16)
__global__ void k_transpose(const float* __restrict__ W, bf16* __restrict__ Wt) {
    __shared__ float tile[32][33];
    int bx = blockIdx.x * 32;   // n
    int by = blockIdx.y * 32;   // k
    int tx = threadIdx.x;
    for (int i = threadIdx.y; i < 32; i += 8)
        tile[i][tx] = W[(size_t)(by + i) * DIM + bx + tx];
    __syncthreads();
    for (int i = threadIdx.y; i < 32; i += 8)
        Wt[(size_t)(bx + i) * DIM + by + tx] = __float2bfloat16(tile[tx][i]);
}

// --------------- merged Q+KV projection GEMM, 2-phase dbuf, FUSED RoPE epilogue
// writes Qb (rope + QSCALE) or KVb (rope) directly in head-major [c][t][d] layout
__launch_bounds__(256, 4)
__global__ void k_gemm_qkv(const bf16* __restrict__ A, const bf16* __restrict__ Bq,
                           const bf16* __restrict__ Bkv, const float* __restrict__ cosT,
                           const float* __restrict__ sinT, bf16* __restrict__ Qb,
                           bf16* __restrict__ KVb) {
    __shared__ alignas(16) bf16 As[2][128 * 32];
    __shared__ alignas(16) bf16 Bs[2][128 * 32];
    const int K = DIM;
    int tid = threadIdx.x;
    int lane = tid & 63, wave = tid >> 6;
    int wr = (wave >> 1) * 64, wc = (wave & 1) * 64;
    int id = blockIdx.x;
    int xcd = id & 7, rank = id >> 3;      // rank 0..127
    int by = xcd * 8 + (rank >> 4);        // 0..63
    int bxx = rank & 15;                   // 0..15 (virtual n block)
    int m0 = by * 128;
    bool isQ = (bxx < 8);
    const bf16* Bt = isQ ? Bq : Bkv;
    int n0 = (bxx & 7) * 128;
    int row = lane & 15, kk = (lane >> 4) * 8;
    int ch0 = wave * 128 + lane, ch1 = ch0 + 64;
    int r0 = ch0 >> 2, c0e = (ch0 & 3) * 8;
    int r1 = ch1 >> 2, c1e = (ch1 & 3) * 8;
    f32x4 acc[4][4] = {};
    gload16(&A[(size_t)(m0 + r0) * K + c0e], &As[0][wave * 1024]);
    gload16(&A[(size_t)(m0 + r1) * K + c1e], &As[0][wave * 1024 + 512]);
    gload16(&Bt[(size_t)(n0 + r0) * K + c0e], &Bs[0][wave * 1024]);
    gload16(&Bt[(size_t)(n0 + r1) * K + c1e], &Bs[0][wave * 1024 + 512]);
    __syncthreads();
    int cur = 0;
    for (int k0 = 0; k0 < K; k0 += 32) {
        int nxt = cur ^ 1;
        if (k0 + 32 < K) {
            gload16(&A[(size_t)(m0 + r0) * K + k0 + 32 + c0e], &As[nxt][wave * 1024]);
            gload16(&A[(size_t)(m0 + r1) * K + k0 + 32 + c1e], &As[nxt][wave * 1024 + 512]);
            gload16(&Bt[(size_t)(n0 + r0) * K + k0 + 32 + c0e], &Bs[nxt][wave * 1024]);
            gload16(&Bt[(size_t)(n0 + r1) * K + k0 + 32 + c1e], &Bs[nxt][wave * 1024 + 512]);
        }
        bf16x8 af[4], bfr[4];
#pragma unroll
        for (int mt = 0; mt < 4; ++mt) af[mt] = *(const bf16x8*)&As[cur][(wr + mt * 16 + row) * 32 + kk];
#pragma unroll
        for (int nt = 0; nt < 4; ++nt) bfr[nt] = *(const bf16x8*)&Bs[cur][(wc + nt * 16 + row) * 32 + kk];
#pragma unroll
        for (int mt = 0; mt < 4; ++mt)
#pragma unroll
            for (int nt = 0; nt < 4; ++nt)
                acc[mt][nt] = __builtin_amdgcn_mfma_f32_16x16x32_bf16(af[mt], bfr[nt], acc[mt][nt], 0, 0, 0);
        __syncthreads();
        cur = nxt;
    }
    // fused RoPE epilogue: cols e=nt*16+ocol (nt<2) pair with e+32 in acc[mt][nt+2]
    int orow = (lane >> 4) * 4, ocol = lane & 15;
    int head_g = (n0 + wc) >> 6;               // 0..15
    float sc = isQ ? QSCALE : 1.0f;
    bf16* Cb = isQ ? Qb : KVb;
#pragma unroll
    for (int mt = 0; mt < 4; ++mt) {
#pragma unroll
        for (int i = 0; i < 4; ++i) {
            int rowg = m0 + wr + mt * 16 + orow + i;
            int t = rowg & (NSEQ - 1), bidx = rowg >> 12;
            int cch = bidx * NH + head_g;
            size_t base = ((size_t)cch * NSEQ + t) * HD;
#pragma unroll
            for (int nt = 0; nt < 2; ++nt) {
                int e = nt * 16 + ocol;
                float x1 = acc[mt][nt][i], x2 = acc[mt][nt + 2][i];
                float cv = cosT[t * 32 + e], sv = sinT[t * 32 + e];
                Cb[base + e]      = __float2bfloat16((x1 * cv - x2 * sv) * sc);
                Cb[base + e + 32] = __float2bfloat16((x2 * cv + x1 * sv) * sc);
            }
        }
    }
}

// final GEMM: 2-phase dbuf, XCD swizzle, per-row-tile weight/bias select, fp32 out
__launch_bounds__(256, 2)
__global__ void k_gemm_out(const bf16* __restrict__ A, const bf16* __restrict__ Bt0,
                           const bf16* __restrict__ Bt1, const float* __restrict__ bias0,
                           const float* __restrict__ bias1, float* __restrict__ C) {
    __shared__ alignas(16) bf16 As[2][128 * 32];
    __shared__ alignas(16) bf16 Bs[2][128 * 32];
    const int K = DIM;
    int tid = threadIdx.x;
    int lane = tid & 63, wave = tid >> 6;
    int wr = (wave >> 1) * 64, wc = (wave & 1) * 64;
    int id = blockIdx.x;                   // 512 blocks
    int xcd = id & 7, rank = id >> 3;      // 0..63
    int by = xcd * 8 + (rank >> 3);        // 0..63
    int bx = rank & 7;
    int m0 = by * 128, n0 = bx * 128;
    bool first = (m0 & (NSEQ - 1)) < MSEG;
    const bf16* Bt = first ? Bt0 : Bt1;
    const float* bias = first ? bias0 : bias1;
    int row = lane & 15, kk = (lane >> 4) * 8;
    int ch0 = wave * 128 + lane, ch1 = ch0 + 64;
    int r0 = ch0 >> 2, c0e = (ch0 & 3) * 8;
    int r1 = ch1 >> 2, c1e = (ch1 & 3) * 8;
    f32x4 acc[4][4] = {};
    gload16(&A[(size_t)(m0 + r0) * K + c0e], &As[0][wave * 1024]);
    gload16(&A[(size_t)(m0 + r1) * K + c1e], &As[0][wave * 1024 + 512]);
    gload16(&Bt[(size_t)(n0 + r0) * K + c0e], &Bs[0][wave * 1024]);
    gload16(&Bt[(size_t)(n0 + r1) * K + c1e], &Bs[0][wave * 1024 + 512]);
    __syncthreads();
    int cur = 0;
    for (int k0 = 0; k0 < K; k0 += 32) {
        int nxt = cur ^ 1;
        if (k0 + 32 < K) {
            gload16(&A[(size_t)(m0 + r0) * K + k0 + 32 + c0e], &As[nxt][wave * 1024]);
            gload16(&A[(size_t)(m0 + r1) * K + k0 + 32 + c1e], &As[nxt][wave * 1024 + 512]);
            gload16(&Bt[(size_t)(n0 + r0) * K + k0 + 32 + c0e], &Bs[nxt][wave * 1024]);
            gload16(&Bt[(size_t)(n0 + r1) * K + k0 + 32 + c1e], &Bs[nxt][wave * 1024 + 512]);
        }
        bf16x8 af[4], bfr[4];
#pragma unroll
        for (int mt = 0; mt < 4; ++mt) af[mt] = *(const bf16x8*)&As[cur][(wr + mt * 16 + row) * 32 + kk];
#pragma unroll
        for (int nt = 0; nt < 4; ++nt) bfr[nt] = *(const bf16x8*)&Bs[cur][(wc + nt * 16 + row) * 32 + kk];
#pragma unroll
        for (int mt = 0; mt < 4; ++mt)
#pragma unroll
            for (int nt = 0; nt < 4; ++nt)
                acc[mt][nt] = __builtin_amdgcn_mfma_f32_16x16x32_bf16(af[mt], bfr[nt], acc[mt][nt], 0, 0, 0);
        __syncthreads();
        cur = nxt;
    }
    int orow = (lane >> 4) * 4, ocol = lane & 15;
#pragma unroll
    for (int mt = 0; mt < 4; ++mt)
#pragma unroll
        for (int nt = 0; nt < 4; ++nt) {
            float bv = bias[n0 + wc + nt * 16 + ocol];
#pragma unroll
            for (int i = 0; i < 4; ++i)
                C[(size_t)(m0 + wr + mt * 16 + orow + i) * DIM + n0 + wc + nt * 16 + ocol] = acc[mt][nt][i] + bv;
        }
}

// --------------------------- KVb -> KVt transpose (LDS-tiled, coalesced both sides)
__global__ void k_kvt(const bf16* __restrict__ KVb, bf16* __restrict__ KVt) {
    __shared__ bf16 T[64][266];
    int c = blockIdx.y, t0 = blockIdx.x * 256;
    int tid = threadIdx.x;
    int dl = (tid & 7) * 8, tl = tid >> 3;     // tl 0..31
#pragma unroll
    for (int it = 0; it < 8; ++it) {
        int tloc = it * 32 + tl;
        union { bf16 h[8]; uint4 u; } v;
        v.u = *(const uint4*)&KVb[((size_t)c * NSEQ + t0 + tloc) * HD + dl];
#pragma unroll
        for (int j = 0; j < 8; ++j) T[dl + j][tloc] = v.h[j];
    }
    __syncthreads();
    int d = tid >> 2, part = tid & 3;
    size_t trow = ((size_t)c * HD + d) * NSEQ + t0;
#pragma unroll
    for (int k = 0; k < 8; ++k) {
        int col = k * 32 + part * 8;
        union { bf16 h[8]; uint4 u; } pk;
#pragma unroll
        for (int j = 0; j < 8; ++j) pk.h[j] = T[d][col + j];
        *(uint4*)&KVt[trow + col] = pk.u;
    }
}

// ---------------------------------------------------------------- attention (swapped-QK 32x32)
// R4/R5 structure: 1024 blocks, LPT heavy-first, XCD-local channels; wave = 32 q-rows.
// + next-tile K register prefetch, V issued after QK (latency hidden under softmax), exp2.
__launch_bounds__(256, 4)
__global__ void k_attn(const bf16* __restrict__ Qb, const bf16* __restrict__ KVb,
                       const bf16* __restrict__ KVt, bf16* __restrict__ Ob) {
    int lane = threadIdx.x & 63, wave = threadIdx.x >> 6;
    int hi = lane >> 5, lq = lane & 31;
    int id = blockIdx.x;
    int xcd = id & 7, rank = id >> 3;           // rank 0..127
    int c = xcd * 4 + (rank & 3);
    int hr = rank >> 2;                         // 0..31, heavy-first
    int bx, seg;
    if (hr < 28) { bx = 3 - hr / 7; seg = 1 + hr % 7; }
    else         { seg = 0; bx = 31 - hr; }
    int i0 = bx * 128 + wave * 32;              // q-row offset within segment
    int bidx = c >> 4, head = c & 15;
    int tq = seg * MSEG + i0 + lq;
    const bf16* qptr = &Qb[((size_t)c * NSEQ + tq) * HD + hi * 8];
    bf16x8 qf[4];
#pragma unroll
    for (int dc = 0; dc < 4; ++dc) qf[dc] = *(const bf16x8*)&qptr[dc * 16];
    f32x16 o0 = {}, o1 = {};
    float mrun = -FLT_MAX, lrun = 0.f;
    int kvbase = (seg == 0) ? 0 : (seg - 1) * MSEG;
    int cstart = (seg == 0) ? 0 : MSEG;
    int cend = cstart + i0 + 32;

    const bf16* kbase = &KVb[((size_t)c * NSEQ + kvbase + lq) * HD + hi * 8];
    const bf16* vbase = &KVt[((size_t)c * HD + lq) * NSEQ + kvbase + hi * 8];

    // preload first K tile
    bf16x8 kf0 = *(const bf16x8*)&kbase[0];
    bf16x8 kf1 = *(const bf16x8*)&kbase[16];
    bf16x8 kf2 = *(const bf16x8*)&kbase[32];
    bf16x8 kf3 = *(const bf16x8*)&kbase[48];

    for (int c0 = 0; c0 < cend; c0 += 32) {
        bool more = (c0 + 32) < cend;
        // prefetch next K tile (in flight across this tile's compute)
        bf16x8 nk0, nk1, nk2, nk3;
        if (more) {
            const bf16* kp = kbase + (size_t)(c0 + 32) * HD;
            nk0 = *(const bf16x8*)&kp[0];
            nk1 = *(const bf16x8*)&kp[16];
            nk2 = *(const bf16x8*)&kp[32];
            nk3 = *(const bf16x8*)&kp[48];
        }
        // ---- S^T[kv][q]
        f32x16 s = {};
        __builtin_amdgcn_s_setprio(1);
        s = __builtin_amdgcn_mfma_f32_32x32x16_bf16(kf0, qf[0], s, 0, 0, 0);
        s = __builtin_amdgcn_mfma_f32_32x32x16_bf16(kf1, qf[1], s, 0, 0, 0);
        s = __builtin_amdgcn_mfma_f32_32x32x16_bf16(kf2, qf[2], s, 0, 0, 0);
        s = __builtin_amdgcn_mfma_f32_32x32x16_bf16(kf3, qf[3], s, 0, 0, 0);
        __builtin_amdgcn_s_setprio(0);
        // ---- current V loads (used ~350 cy later in PV; latency hides under softmax)
        const bf16* vp = vbase + c0;
        bf16x8 vf0 = *(const bf16x8*)&vp[0];
        bf16x8 vf1 = *(const bf16x8*)&vp[16];
        bf16x8 vf2 = *(const bf16x8*)&vp[(size_t)32 * NSEQ];
        bf16x8 vf3 = *(const bf16x8*)&vp[(size_t)32 * NSEQ + 16];
        // ---- causal mask (boundary tiles only)
        if (c0 + 31 >= cstart && c0 + 31 - cstart > i0) {
#pragma unroll
            for (int r = 0; r < 16; ++r) {
                int kvg = c0 + ((r & 3) + 8 * (r >> 2) + 4 * hi);
                if (kvg >= cstart && kvg - cstart > i0 + lq) s[r] = -FLT_MAX;
            }
        }
        // ---- online softmax (base-2; log2e folded into Q), defer-max
        float m8[8], m4[4];
#pragma unroll
        for (int r = 0; r < 8; ++r) m8[r] = fmaxf(s[2 * r], s[2 * r + 1]);
#pragma unroll
        for (int r = 0; r < 4; ++r) m4[r] = fmaxf(m8[2 * r], m8[2 * r + 1]);
        float vmax = fmaxf(fmaxf(m4[0], m4[1]), fmaxf(m4[2], m4[3]));
        vmax = fmaxf(vmax, __shfl_xor(vmax, 32));
        if (__any(vmax > mrun + 11.5f)) {
            float nm = fmaxf(mrun, vmax);
            float al = fast_exp2(mrun - nm);
#pragma unroll
            for (int r = 0; r < 16; ++r) { o0[r] *= al; o1[r] *= al; }
            lrun *= al;
            mrun = nm;
        }
        float p[16];
#pragma unroll
        for (int r = 0; r < 16; ++r) p[r] = fast_exp2(s[r] - mrun);
        float a8[8], a4[4];
#pragma unroll
        for (int r = 0; r < 8; ++r) a8[r] = p[2 * r] + p[2 * r + 1];
#pragma unroll
        for (int r = 0; r < 4; ++r) a4[r] = a8[2 * r] + a8[2 * r + 1];
        lrun += (a4[0] + a4[1]) + (a4[2] + a4[3]);
        // ---- P^T -> B-fragment (pack + half-exchange, 4 shfl)
        unsigned pk[8];
#pragma unroll
        for (int k = 0; k < 8; ++k) {
            union { bf16 h[2]; unsigned u; } cv;
            cv.h[0] = __float2bfloat16(p[2 * k]);
            cv.h[1] = __float2bfloat16(p[2 * k + 1]);
            pk[k] = cv.u;
        }
        unsigned u0 = hi ? pk[0] : pk[2];
        unsigned u1 = hi ? pk[1] : pk[3];
        unsigned u2 = hi ? pk[4] : pk[6];
        unsigned u3 = hi ? pk[5] : pk[7];
        unsigned w0 = (unsigned)__shfl_xor((int)u0, 32);
        unsigned w1 = (unsigned)__shfl_xor((int)u1, 32);
        unsigned w2 = (unsigned)__shfl_xor((int)u2, 32);
        unsigned w3 = (unsigned)__shfl_xor((int)u3, 32);
        union { unsigned u[4]; bf16x8 v; } b0, b1;
        if (hi == 0) {
            b0.u[0] = pk[0]; b0.u[1] = pk[1]; b0.u[2] = w0; b0.u[3] = w1;
            b1.u[0] = pk[4]; b1.u[1] = pk[5]; b1.u[2] = w2; b1.u[3] = w3;
        } else {
            b0.u[0] = w0; b0.u[1] = w1; b0.u[2] = pk[2]; b0.u[3] = pk[3];
            b1.u[0] = w2; b1.u[1] = w3; b1.u[2] = pk[6]; b1.u[3] = pk[7];
        }
        // ---- O^T[d][q] += V^T P^T
        __builtin_amdgcn_s_setprio(1);
        o0 = __builtin_amdgcn_mfma_f32_32x32x16_bf16(vf0, b0.v, o0, 0, 0, 0);
        o1 = __builtin_amdgcn_mfma_f32_32x32x16_bf16(vf2, b0.v, o1, 0, 0, 0);
        o0 = __builtin_amdgcn_mfma_f32_32x32x16_bf16(vf1, b1.v, o0, 0, 0, 0);
        o1 = __builtin_amdgcn_mfma_f32_32x32x16_bf16(vf3, b1.v, o1, 0, 0, 0);
        __builtin_amdgcn_s_setprio(0);
        if (more) { kf0 = nk0; kf1 = nk1; kf2 = nk2; kf3 = nk3; }
    }
    lrun += __shfl_xor(lrun, 32);
    float inv = 1.0f / lrun;
    size_t obase = ((size_t)bidx * NSEQ + tq) * DIM + head * HD;
#pragma unroll
    for (int dt = 0; dt < 2; ++dt)
#pragma unroll
        for (int a = 0; a < 4; ++a) {
            union { bf16 h[4]; uint2 u; } pkd;
            const f32x16& ov = dt ? o1 : o0;
#pragma unroll
            for (int i = 0; i < 4; ++i) pkd.h[i] = __float2bfloat16(ov[4 * a + i] * inv);
            *(uint2*)&Ob[obase + dt * 32 + 8 * a + 4 * hi] = pkd.u;
        }
}

// ---------------------------------------------------------------- launch
extern "C" void kernel_launch(void* const* d_in, const int* in_sizes, int n_in,
                              void* d_out, int out_size, void* d_ws, size_t ws_size,
                              hipStream_t stream) {
    const float* x   = (const float*)d_in[0];
    const float* Wq  = (const float*)d_in[1];
    const float* Wkv = (const float*)d_in[2];
    const float* Wo  = (const float*)d_in[3];
    const float* bo  = (const float*)d_in[4];
    const float* Wo0 = (const float*)d_in[5];
    const float* bo0 = (const float*)d_in[6];
    float* out = (float*)d_out;

    char* ws = (char*)d_ws;
    size_t off = 0;
    auto alloc = [&](size_t bytes) { void* p = ws + off; off += (bytes + 255) & ~(size_t)255; return p; };
    float* cosT = (float*)alloc((size_t)NSEQ * 32 * 4);
    float* sinT = (float*)alloc((size_t)NSEQ * 32 * 4);
    bf16* Xb    = (bf16*)alloc((size_t)ROWS * DIM * 2);
    bf16* WqT   = (bf16*)alloc((size_t)DIM * DIM * 2);
    bf16* WkvT  = (bf16*)alloc((size_t)DIM * DIM * 2);
    bf16* WoT   = (bf16*)alloc((size_t)DIM * DIM * 2);
    bf16* Wo0T  = (bf16*)alloc((size_t)DIM * DIM * 2);
    bf16* Qb    = (bf16*)alloc((size_t)NC * NSEQ * HD * 2);
    bf16* KVb   = (bf16*)alloc((size_t)NC * NSEQ * HD * 2);
    bf16* KVt   = (bf16*)alloc((size_t)NC * HD * NSEQ * 2);
    bf16* Ob    = (bf16*)alloc((size_t)ROWS * DIM * 2);

    hipLaunchKernelGGL(k_rope_tab, dim3(NSEQ * 32 / 256), dim3(256), 0, stream, cosT, sinT);
    hipLaunchKernelGGL(k_convert_x, dim3(ROWS * DIM / 4 / 256), dim3(256), 0, stream, x, Xb);
    hipLaunchKernelGGL(k_transpose, dim3(32, 32), dim3(32, 8), 0, stream, Wq, WqT);
    hipLaunchKernelGGL(k_transpose, dim3(32, 32), dim3(32, 8), 0, stream, Wkv, WkvT);
    hipLaunchKernelGGL(k_transpose, dim3(32, 32), dim3(32, 8), 0, stream, Wo, WoT);
    hipLaunchKernelGGL(k_transpose, dim3(32, 32), dim3(32, 8), 0, stream, Wo0, Wo0T);

    hipLaunchKernelGGL(k_gemm_qkv, dim3(1024), dim3(256), 0, stream, Xb, WqT, WkvT, cosT, sinT, Qb, KVb);
    hipLaunchKernelGGL(k_kvt, dim3(16, 32), dim3(256), 0, stream, KVb, KVt);

    hipLaunchKernelGGL(k_attn, dim3(1024), dim3(256), 0, stream, Qb, KVb, KVt, Ob);

    hipLaunchKernelGGL(k_gemm_out, dim3(512), dim3(256), 0, stream, Ob, Wo0T, WoT, bo0, bo, out);
}

// Round 9
// 170.201 us; speedup vs baseline: 2.1106x; 1.1936x over previous
//
#include <hip/hip_runtime.h>
#include <hip/hip_bf16.h>
#include <float.h>

using bf16 = __hip_bfloat16;
typedef __attribute__((ext_vector_type(8))) short bf16x8;
typedef __attribute__((ext_vector_type(4))) float f32x4;
typedef __attribute__((ext_vector_type(16))) float f32x16;

#define DIM   1024
#define NSEQ  4096
#define BATCH 2
#define NH    16
#define HD    64
#define NSEG  8
#define MSEG  512
#define ROWS  (BATCH*NSEQ)   // 8192
#define NC    (BATCH*NH)     // 32
#define QSCALE (0.125f * 1.44269504f)   // d^-0.5 * log2(e)  (exp2 softmax)

__device__ __forceinline__ float fast_exp2(float x) {
    float r;
    asm volatile("v_exp_f32 %0, %1" : "=v"(r) : "v"(x));
    return r;
}

__device__ __forceinline__ void gload16(const bf16* g, bf16* l) {
    __builtin_amdgcn_global_load_lds((const __attribute__((address_space(1))) unsigned int*)g,
                                     (__attribute__((address_space(3))) unsigned int*)l, 16, 0, 0);
}

// ---------------------------------------------------------------- rope table
__global__ void k_rope_tab(float* __restrict__ cosT, float* __restrict__ sinT) {
    int idx = blockIdx.x * 256 + threadIdx.x;     // 4096*32 = 131072
    int t = idx >> 5, i = idx & 31;
    float freq = 1.0f / powf(10000.0f, (float)(2 * i) * (1.0f / 64.0f));
    float a = (float)t * freq;
    cosT[idx] = cosf(a);
    sinT[idx] = sinf(a);
}

// ---------------------------------------------------------------- x -> bf16
__global__ void k_convert_x(const float* __restrict__ X, bf16* __restrict__ Xb) {
    int i = (blockIdx.x * 256 + threadIdx.x) * 4;
    float4 v = *(const float4*)&X[i];
    union { bf16 h[4]; uint2 u; } p;
    p.h[0] = __float2bfloat16(v.x);
    p.h[1] = __float2bfloat16(v.y);
    p.h[2] = __float2bfloat16(v.z);
    p.h[3] = __float2bfloat16(v.w);
    *(uint2*)&Xb[i] = p.u;
}

// ------------------------------------------- W[k][n] -> Wt[n][k] (bf16)
__global__ void k_transpose(const float* __restrict__ W, bf16* __restrict__ Wt) {
    __shared__ float tile[32][33];
    int bx = blockIdx.x * 32;   // n
    int by = blockIdx.y * 32;   // k
    int tx = threadIdx.x;
    for (int i = threadIdx.y; i < 32; i += 8)
        tile[i][tx] = W[(size_t)(by + i) * DIM + bx + tx];
    __syncthreads();
    for (int i = threadIdx.y; i < 32; i += 8)
        Wt[(size_t)(bx + i) * DIM + by + tx] = __float2bfloat16(tile[tx][i]);
}

// --------------- merged Q+KV projection GEMM, 2-phase dbuf, FUSED RoPE epilogue
__launch_bounds__(256, 4)
__global__ void k_gemm_qkv(const bf16* __restrict__ A, const bf16* __restrict__ Bq,
                           const bf16* __restrict__ Bkv, const float* __restrict__ cosT,
                           const float* __restrict__ sinT, bf16* __restrict__ Qb,
                           bf16* __restrict__ KVb) {
    __shared__ alignas(16) bf16 As[2][128 * 32];
    __shared__ alignas(16) bf16 Bs[2][128 * 32];
    const int K = DIM;
    int tid = threadIdx.x;
    int lane = tid & 63, wave = tid >> 6;
    int wr = (wave >> 1) * 64, wc = (wave & 1) * 64;
    int id = blockIdx.x;
    int xcd = id & 7, rank = id >> 3;      // rank 0..127
    int by = xcd * 8 + (rank >> 4);        // 0..63
    int bxx = rank & 15;                   // 0..15 (virtual n block)
    int m0 = by * 128;
    bool isQ = (bxx < 8);
    const bf16* Bt = isQ ? Bq : Bkv;
    int n0 = (bxx & 7) * 128;
    int row = lane & 15, kk = (lane >> 4) * 8;
    int ch0 = wave * 128 + lane, ch1 = ch0 + 64;
    int r0 = ch0 >> 2, c0e = (ch0 & 3) * 8;
    int r1 = ch1 >> 2, c1e = (ch1 & 3) * 8;
    f32x4 acc[4][4] = {};
    gload16(&A[(size_t)(m0 + r0) * K + c0e], &As[0][wave * 1024]);
    gload16(&A[(size_t)(m0 + r1) * K + c1e], &As[0][wave * 1024 + 512]);
    gload16(&Bt[(size_t)(n0 + r0) * K + c0e], &Bs[0][wave * 1024]);
    gload16(&Bt[(size_t)(n0 + r1) * K + c1e], &Bs[0][wave * 1024 + 512]);
    __syncthreads();
    int cur = 0;
    for (int k0 = 0; k0 < K; k0 += 32) {
        int nxt = cur ^ 1;
        if (k0 + 32 < K) {
            gload16(&A[(size_t)(m0 + r0) * K + k0 + 32 + c0e], &As[nxt][wave * 1024]);
            gload16(&A[(size_t)(m0 + r1) * K + k0 + 32 + c1e], &As[nxt][wave * 1024 + 512]);
            gload16(&Bt[(size_t)(n0 + r0) * K + k0 + 32 + c0e], &Bs[nxt][wave * 1024]);
            gload16(&Bt[(size_t)(n0 + r1) * K + k0 + 32 + c1e], &Bs[nxt][wave * 1024 + 512]);
        }
        bf16x8 af[4], bfr[4];
#pragma unroll
        for (int mt = 0; mt < 4; ++mt) af[mt] = *(const bf16x8*)&As[cur][(wr + mt * 16 + row) * 32 + kk];
#pragma unroll
        for (int nt = 0; nt < 4; ++nt) bfr[nt] = *(const bf16x8*)&Bs[cur][(wc + nt * 16 + row) * 32 + kk];
#pragma unroll
        for (int mt = 0; mt < 4; ++mt)
#pragma unroll
            for (int nt = 0; nt < 4; ++nt)
                acc[mt][nt] = __builtin_amdgcn_mfma_f32_16x16x32_bf16(af[mt], bfr[nt], acc[mt][nt], 0, 0, 0);
        __syncthreads();
        cur = nxt;
    }
    // fused RoPE epilogue: cols e=nt*16+ocol (nt<2) pair with e+32 in acc[mt][nt+2]
    int orow = (lane >> 4) * 4, ocol = lane & 15;
    int head_g = (n0 + wc) >> 6;               // 0..15
    float sc = isQ ? QSCALE : 1.0f;
    bf16* Cb = isQ ? Qb : KVb;
#pragma unroll
    for (int mt = 0; mt < 4; ++mt) {
#pragma unroll
        for (int i = 0; i < 4; ++i) {
            int rowg = m0 + wr + mt * 16 + orow + i;
            int t = rowg & (NSEQ - 1), bidx = rowg >> 12;
            int cch = bidx * NH + head_g;
            size_t base = ((size_t)cch * NSEQ + t) * HD;
#pragma unroll
            for (int nt = 0; nt < 2; ++nt) {
                int e = nt * 16 + ocol;
                float x1 = acc[mt][nt][i], x2 = acc[mt][nt + 2][i];
                float cv = cosT[t * 32 + e], sv = sinT[t * 32 + e];
                Cb[base + e]      = __float2bfloat16((x1 * cv - x2 * sv) * sc);
                Cb[base + e + 32] = __float2bfloat16((x2 * cv + x1 * sv) * sc);
            }
        }
    }
}

// final GEMM: 2-phase dbuf, XCD swizzle, per-row-tile weight/bias select, fp32 out
__launch_bounds__(256, 2)
__global__ void k_gemm_out(const bf16* __restrict__ A, const bf16* __restrict__ Bt0,
                           const bf16* __restrict__ Bt1, const float* __restrict__ bias0,
                           const float* __restrict__ bias1, float* __restrict__ C) {
    __shared__ alignas(16) bf16 As[2][128 * 32];
    __shared__ alignas(16) bf16 Bs[2][128 * 32];
    const int K = DIM;
    int tid = threadIdx.x;
    int lane = tid & 63, wave = tid >> 6;
    int wr = (wave >> 1) * 64, wc = (wave & 1) * 64;
    int id = blockIdx.x;                   // 512 blocks
    int xcd = id & 7, rank = id >> 3;      // 0..63
    int by = xcd * 8 + (rank >> 3);        // 0..63
    int bx = rank & 7;
    int m0 = by * 128, n0 = bx * 128;
    bool first = (m0 & (NSEQ - 1)) < MSEG;
    const bf16* Bt = first ? Bt0 : Bt1;
    const float* bias = first ? bias0 : bias1;
    int row = lane & 15, kk = (lane >> 4) * 8;
    int ch0 = wave * 128 + lane, ch1 = ch0 + 64;
    int r0 = ch0 >> 2, c0e = (ch0 & 3) * 8;
    int r1 = ch1 >> 2, c1e = (ch1 & 3) * 8;
    f32x4 acc[4][4] = {};
    gload16(&A[(size_t)(m0 + r0) * K + c0e], &As[0][wave * 1024]);
    gload16(&A[(size_t)(m0 + r1) * K + c1e], &As[0][wave * 1024 + 512]);
    gload16(&Bt[(size_t)(n0 + r0) * K + c0e], &Bs[0][wave * 1024]);
    gload16(&Bt[(size_t)(n0 + r1) * K + c1e], &Bs[0][wave * 1024 + 512]);
    __syncthreads();
    int cur = 0;
    for (int k0 = 0; k0 < K; k0 += 32) {
        int nxt = cur ^ 1;
        if (k0 + 32 < K) {
            gload16(&A[(size_t)(m0 + r0) * K + k0 + 32 + c0e], &As[nxt][wave * 1024]);
            gload16(&A[(size_t)(m0 + r1) * K + k0 + 32 + c1e], &As[nxt][wave * 1024 + 512]);
            gload16(&Bt[(size_t)(n0 + r0) * K + k0 + 32 + c0e], &Bs[nxt][wave * 1024]);
            gload16(&Bt[(size_t)(n0 + r1) * K + k0 + 32 + c1e], &Bs[nxt][wave * 1024 + 512]);
        }
        bf16x8 af[4], bfr[4];
#pragma unroll
        for (int mt = 0; mt < 4; ++mt) af[mt] = *(const bf16x8*)&As[cur][(wr + mt * 16 + row) * 32 + kk];
#pragma unroll
        for (int nt = 0; nt < 4; ++nt) bfr[nt] = *(const bf16x8*)&Bs[cur][(wc + nt * 16 + row) * 32 + kk];
#pragma unroll
        for (int mt = 0; mt < 4; ++mt)
#pragma unroll
            for (int nt = 0; nt < 4; ++nt)
                acc[mt][nt] = __builtin_amdgcn_mfma_f32_16x16x32_bf16(af[mt], bfr[nt], acc[mt][nt], 0, 0, 0);
        __syncthreads();
        cur = nxt;
    }
    int orow = (lane >> 4) * 4, ocol = lane & 15;
#pragma unroll
    for (int mt = 0; mt < 4; ++mt)
#pragma unroll
        for (int nt = 0; nt < 4; ++nt) {
            float bv = bias[n0 + wc + nt * 16 + ocol];
#pragma unroll
            for (int i = 0; i < 4; ++i)
                C[(size_t)(m0 + wr + mt * 16 + orow + i) * DIM + n0 + wc + nt * 16 + ocol] = acc[mt][nt][i] + bv;
        }
}

// --------------- K/V fragment pre-pack: KVf[c][tile][frag 0-7][lane][8]
// frag f<4 : K A-operand  — lane(hi,lq) holds KVb[c][tile*32+lq][f*16+hi*8 ..+8]
// frag 4+m : V^T A-operand — lane holds V[t=tile*32+(m&1)*16+hi*8+j][d=(m>>1)*32+lq]
// Each fragment = 64 lanes x 16B contiguous -> attn loads are fully coalesced.
__global__ void k_pack(const bf16* __restrict__ KVb, bf16* __restrict__ KVf) {
    __shared__ bf16 T[256][72];
    int c = blockIdx.y, t0 = blockIdx.x * 256;
    int tid = threadIdx.x;
    int r = tid >> 3, cc = (tid & 7) * 8;
#pragma unroll
    for (int it = 0; it < 8; ++it) {
        int row = it * 32 + r;
        *(bf16x8*)&T[row][cc] = *(const bf16x8*)&KVb[((size_t)c * NSEQ + t0 + row) * HD + cc];
    }
    __syncthreads();
    int lane = tid & 63, wave = tid >> 6;
    int hi = lane >> 5, lq = lane & 31;
    size_t base = (((size_t)c * 128 + (t0 >> 5)) * 8) * 512;   // elements
    for (int tl = wave * 2; tl < wave * 2 + 2; ++tl) {
        size_t tb = base + (size_t)tl * 4096;
#pragma unroll
        for (int f = 0; f < 4; ++f) {
            bf16x8 v = *(const bf16x8*)&T[tl * 32 + lq][f * 16 + hi * 8];
            *(bf16x8*)&KVf[tb + (size_t)f * 512 + lane * 8] = v;
        }
#pragma unroll
        for (int m = 0; m < 4; ++m) {
            int d0 = (m >> 1) * 32, sub = m & 1;
            union { bf16 h[8]; bf16x8 v; } pk;
#pragma unroll
            for (int j = 0; j < 8; ++j)
                pk.h[j] = T[tl * 32 + sub * 16 + hi * 8 + j][d0 + lq];
            *(bf16x8*)&KVf[tb + (size_t)(4 + m) * 512 + lane * 8] = pk.v;
        }
    }
}

// ---------------------------------------------------------------- attention (swapped-QK 32x32)
// 1024 blocks, LPT heavy-first, XCD-local channels; wave = 32 q-rows.
// All K/V loads from fragment-packed KVf (coalesced 1KB/instr); next-K prefetch; exp2 softmax.
__launch_bounds__(256, 4)
__global__ void k_attn(const bf16* __restrict__ Qb, const bf16* __restrict__ KVf,
                       bf16* __restrict__ Ob) {
    int lane = threadIdx.x & 63, wave = threadIdx.x >> 6;
    int hi = lane >> 5, lq = lane & 31;
    int id = blockIdx.x;
    int xcd = id & 7, rank = id >> 3;           // rank 0..127
    int c = xcd * 4 + (rank & 3);
    int hr = rank >> 2;                         // 0..31, heavy-first
    int bx, seg;
    if (hr < 28) { bx = 3 - hr / 7; seg = 1 + hr % 7; }
    else         { seg = 0; bx = 31 - hr; }
    int i0 = bx * 128 + wave * 32;              // q-row offset within segment
    int bidx = c >> 4, head = c & 15;
    int tq = seg * MSEG + i0 + lq;
    const bf16* qptr = &Qb[((size_t)c * NSEQ + tq) * HD + hi * 8];
    bf16x8 qf[4];
#pragma unroll
    for (int dc = 0; dc < 4; ++dc) qf[dc] = *(const bf16x8*)&qptr[dc * 16];
    f32x16 o0 = {}, o1 = {};
    float mrun = -FLT_MAX, lrun = 0.f;
    int kvbase = (seg == 0) ? 0 : (seg - 1) * MSEG;
    int cstart = (seg == 0) ? 0 : MSEG;
    int cend = cstart + i0 + 32;
    int nT = cend >> 5;                         // number of 32-kv tiles

    const bf16* fb = &KVf[((size_t)c * 128 + (kvbase >> 5)) * 4096 + lane * 8];

    // preload first K tile (frags 0-3)
    bf16x8 kf0 = *(const bf16x8*)&fb[0];
    bf16x8 kf1 = *(const bf16x8*)&fb[512];
    bf16x8 kf2 = *(const bf16x8*)&fb[1024];
    bf16x8 kf3 = *(const bf16x8*)&fb[1536];

    for (int it = 0; it < nT; ++it) {
        int c0 = it * 32;
        bool more = (it + 1) < nT;
        // prefetch next K tile
        bf16x8 nk0, nk1, nk2, nk3;
        if (more) {
            const bf16* pn = fb + (size_t)(it + 1) * 4096;
            nk0 = *(const bf16x8*)&pn[0];
            nk1 = *(const bf16x8*)&pn[512];
            nk2 = *(const bf16x8*)&pn[1024];
            nk3 = *(const bf16x8*)&pn[1536];
        }
        // ---- S^T[kv][q]
        f32x16 s = {};
        __builtin_amdgcn_s_setprio(1);
        s = __builtin_amdgcn_mfma_f32_32x32x16_bf16(kf0, qf[0], s, 0, 0, 0);
        s = __builtin_amdgcn_mfma_f32_32x32x16_bf16(kf1, qf[1], s, 0, 0, 0);
        s = __builtin_amdgcn_mfma_f32_32x32x16_bf16(kf2, qf[2], s, 0, 0, 0);
        s = __builtin_amdgcn_mfma_f32_32x32x16_bf16(kf3, qf[3], s, 0, 0, 0);
        __builtin_amdgcn_s_setprio(0);
        // ---- current V tile (frags 4-7); consumed after softmax (~300cy, L2-hit hidden)
        const bf16* pv = fb + (size_t)it * 4096 + 2048;
        bf16x8 vf0 = *(const bf16x8*)&pv[0];
        bf16x8 vf1 = *(const bf16x8*)&pv[512];
        bf16x8 vf2 = *(const bf16x8*)&pv[1024];
        bf16x8 vf3 = *(const bf16x8*)&pv[1536];
        // ---- causal mask (boundary tiles only)
        if (c0 + 31 >= cstart && c0 + 31 - cstart > i0) {
#pragma unroll
            for (int r = 0; r < 16; ++r) {
                int kvg = c0 + ((r & 3) + 8 * (r >> 2) + 4 * hi);
                if (kvg >= cstart && kvg - cstart > i0 + lq) s[r] = -FLT_MAX;
            }
        }
        // ---- online softmax (base-2), defer-max
        float m8[8], m4[4];
#pragma unroll
        for (int r = 0; r < 8; ++r) m8[r] = fmaxf(s[2 * r], s[2 * r + 1]);
#pragma unroll
        for (int r = 0; r < 4; ++r) m4[r] = fmaxf(m8[2 * r], m8[2 * r + 1]);
        float vmax = fmaxf(fmaxf(m4[0], m4[1]), fmaxf(m4[2], m4[3]));
        vmax = fmaxf(vmax, __shfl_xor(vmax, 32));
        if (__any(vmax > mrun + 11.5f)) {
            float nm = fmaxf(mrun, vmax);
            float al = fast_exp2(mrun - nm);
#pragma unroll
            for (int r = 0; r < 16; ++r) { o0[r] *= al; o1[r] *= al; }
            lrun *= al;
            mrun = nm;
        }
        float p[16];
#pragma unroll
        for (int r = 0; r < 16; ++r) p[r] = fast_exp2(s[r] - mrun);
        float a8[8], a4[4];
#pragma unroll
        for (int r = 0; r < 8; ++r) a8[r] = p[2 * r] + p[2 * r + 1];
#pragma unroll
        for (int r = 0; r < 4; ++r) a4[r] = a8[2 * r] + a8[2 * r + 1];
        lrun += (a4[0] + a4[1]) + (a4[2] + a4[3]);
        // ---- P^T -> B-fragment (pack + half-exchange, 4 shfl, branch-free select)
        unsigned pk[8];
#pragma unroll
        for (int k = 0; k < 8; ++k) {
            union { bf16 h[2]; unsigned u; } cv;
            cv.h[0] = __float2bfloat16(p[2 * k]);
            cv.h[1] = __float2bfloat16(p[2 * k + 1]);
            pk[k] = cv.u;
        }
        unsigned u0 = hi ? pk[0] : pk[2];
        unsigned u1 = hi ? pk[1] : pk[3];
        unsigned u2 = hi ? pk[4] : pk[6];
        unsigned u3 = hi ? pk[5] : pk[7];
        unsigned w0 = (unsigned)__shfl_xor((int)u0, 32);
        unsigned w1 = (unsigned)__shfl_xor((int)u1, 32);
        unsigned w2 = (unsigned)__shfl_xor((int)u2, 32);
        unsigned w3 = (unsigned)__shfl_xor((int)u3, 32);
        union { unsigned u[4]; bf16x8 v; } b0, b1;
        b0.u[0] = hi ? w0 : pk[0];
        b0.u[1] = hi ? w1 : pk[1];
        b0.u[2] = hi ? pk[2] : w0;
        b0.u[3] = hi ? pk[3] : w1;
        b1.u[0] = hi ? w2 : pk[4];
        b1.u[1] = hi ? w3 : pk[5];
        b1.u[2] = hi ? pk[6] : w2;
        b1.u[3] = hi ? pk[7] : w3;
        // ---- O^T[d][q] += V^T P^T
        __builtin_amdgcn_s_setprio(1);
        o0 = __builtin_amdgcn_mfma_f32_32x32x16_bf16(vf0, b0.v, o0, 0, 0, 0);
        o1 = __builtin_amdgcn_mfma_f32_32x32x16_bf16(vf2, b0.v, o1, 0, 0, 0);
        o0 = __builtin_amdgcn_mfma_f32_32x32x16_bf16(vf1, b1.v, o0, 0, 0, 0);
        o1 = __builtin_amdgcn_mfma_f32_32x32x16_bf16(vf3, b1.v, o1, 0, 0, 0);
        __builtin_amdgcn_s_setprio(0);
        if (more) { kf0 = nk0; kf1 = nk1; kf2 = nk2; kf3 = nk3; }
    }
    lrun += __shfl_xor(lrun, 32);
    float inv = 1.0f / lrun;
    size_t obase = ((size_t)bidx * NSEQ + tq) * DIM + head * HD;
#pragma unroll
    for (int dt = 0; dt < 2; ++dt)
#pragma unroll
        for (int a = 0; a < 4; ++a) {
            union { bf16 h[4]; uint2 u; } pkd;
            const f32x16& ov = dt ? o1 : o0;
#pragma unroll
            for (int i = 0; i < 4; ++i) pkd.h[i] = __float2bfloat16(ov[4 * a + i] * inv);
            *(uint2*)&Ob[obase + dt * 32 + 8 * a + 4 * hi] = pkd.u;
        }
}

// ---------------------------------------------------------------- launch
extern "C" void kernel_launch(void* const* d_in, const int* in_sizes, int n_in,
                              void* d_out, int out_size, void* d_ws, size_t ws_size,
                              hipStream_t stream) {
    const float* x   = (const float*)d_in[0];
    const float* Wq  = (const float*)d_in[1];
    const float* Wkv = (const float*)d_in[2];
    const float* Wo  = (const float*)d_in[3];
    const float* bo  = (const float*)d_in[4];
    const float* Wo0 = (const float*)d_in[5];
    const float* bo0 = (const float*)d_in[6];
    float* out = (float*)d_out;

    char* ws = (char*)d_ws;
    size_t off = 0;
    auto alloc = [&](size_t bytes) { void* p = ws + off; off += (bytes + 255) & ~(size_t)255; return p; };
    float* cosT = (float*)alloc((size_t)NSEQ * 32 * 4);
    float* sinT = (float*)alloc((size_t)NSEQ * 32 * 4);
    bf16* Xb    = (bf16*)alloc((size_t)ROWS * DIM * 2);
    bf16* WqT   = (bf16*)alloc((size_t)DIM * DIM * 2);
    bf16* WkvT  = (bf16*)alloc((size_t)DIM * DIM * 2);
    bf16* WoT   = (bf16*)alloc((size_t)DIM * DIM * 2);
    bf16* Wo0T  = (bf16*)alloc((size_t)DIM * DIM * 2);
    bf16* Qb    = (bf16*)alloc((size_t)NC * NSEQ * HD * 2);
    bf16* KVb   = (bf16*)alloc((size_t)NC * NSEQ * HD * 2);
    bf16* KVf   = (bf16*)alloc((size_t)NC * 128 * 4096 * 2);
    bf16* Ob    = (bf16*)alloc((size_t)ROWS * DIM * 2);

    hipLaunchKernelGGL(k_rope_tab, dim3(NSEQ * 32 / 256), dim3(256), 0, stream, cosT, sinT);
    hipLaunchKernelGGL(k_convert_x, dim3(ROWS * DIM / 4 / 256), dim3(256), 0, stream, x, Xb);
    hipLaunchKernelGGL(k_transpose, dim3(32, 32), dim3(32, 8), 0, stream, Wq, WqT);
    hipLaunchKernelGGL(k_transpose, dim3(32, 32), dim3(32, 8), 0, stream, Wkv, WkvT);
    hipLaunchKernelGGL(k_transpose, dim3(32, 32), dim3(32, 8), 0, stream, Wo, WoT);
    hipLaunchKernelGGL(k_transpose, dim3(32, 32), dim3(32, 8), 0, stream, Wo0, Wo0T);

    hipLaunchKernelGGL(k_gemm_qkv, dim3(1024), dim3(256), 0, stream, Xb, WqT, WkvT, cosT, sinT, Qb, KVb);
    hipLaunchKernelGGL(k_pack, dim3(16, 32), dim3(256), 0, stream, KVb, KVf);

    hipLaunchKernelGGL(k_attn, dim3(1024), dim3(256), 0, stream, Qb, KVf, Ob);

    hipLaunchKernelGGL(k_gemm_out, dim3(512), dim3(256), 0, stream, Ob, Wo0T, WoT, bo0, bo, out);
}

// Round 10
// 161.360 us; speedup vs baseline: 2.2262x; 1.0548x over previous
//
#include <hip/hip_runtime.h>
#include <hip/hip_bf16.h>
#include <float.h>

using bf16 = __hip_bfloat16;
typedef __attribute__((ext_vector_type(8))) short bf16x8;
typedef __attribute__((ext_vector_type(4))) float f32x4;
typedef __attribute__((ext_vector_type(16))) float f32x16;

#define DIM   1024
#define NSEQ  4096
#define BATCH 2
#define NH    16
#define HD    64
#define NSEG  8
#define MSEG  512
#define ROWS  (BATCH*NSEQ)   // 8192
#define NC    (BATCH*NH)     // 32
#define QSCALE (0.125f * 1.44269504f)   // d^-0.5 * log2(e)  (exp2 softmax)

__device__ __forceinline__ float fast_exp2(float x) {
    float r;
    asm volatile("v_exp_f32 %0, %1" : "=v"(r) : "v"(x));
    return r;
}

__device__ __forceinline__ void gload16(const bf16* g, bf16* l) {
    __builtin_amdgcn_global_load_lds((const __attribute__((address_space(1))) unsigned int*)g,
                                     (__attribute__((address_space(3))) unsigned int*)l, 16, 0, 0);
}

// ---------------------------------------------------------------- rope table
__global__ void k_rope_tab(float* __restrict__ cosT, float* __restrict__ sinT) {
    int idx = blockIdx.x * 256 + threadIdx.x;     // 4096*32 = 131072
    int t = idx >> 5, i = idx & 31;
    float freq = 1.0f / powf(10000.0f, (float)(2 * i) * (1.0f / 64.0f));
    float a = (float)t * freq;
    cosT[idx] = cosf(a);
    sinT[idx] = sinf(a);
}

// ---------------------------------------------------------------- x -> bf16
__global__ void k_convert_x(const float* __restrict__ X, bf16* __restrict__ Xb) {
    int i = (blockIdx.x * 256 + threadIdx.x) * 4;
    float4 v = *(const float4*)&X[i];
    union { bf16 h[4]; uint2 u; } p;
    p.h[0] = __float2bfloat16(v.x);
    p.h[1] = __float2bfloat16(v.y);
    p.h[2] = __float2bfloat16(v.z);
    p.h[3] = __float2bfloat16(v.w);
    *(uint2*)&Xb[i] = p.u;
}

// ------------------------------------------- W[k][n] -> Wt[n][k] (bf16)
__global__ void k_transpose(const float* __restrict__ W, bf16* __restrict__ Wt) {
    __shared__ float tile[32][33];
    int bx = blockIdx.x * 32;   // n
    int by = blockIdx.y * 32;   // k
    int tx = threadIdx.x;
    for (int i = threadIdx.y; i < 32; i += 8)
        tile[i][tx] = W[(size_t)(by + i) * DIM + bx + tx];
    __syncthreads();
    for (int i = threadIdx.y; i < 32; i += 8)
        Wt[(size_t)(bx + i) * DIM + by + tx] = __float2bfloat16(tile[tx][i]);
}

// --------------- merged Q+KV projection GEMM, 2-phase dbuf, FUSED RoPE epilogue
__launch_bounds__(256, 4)
__global__ void k_gemm_qkv(const bf16* __restrict__ A, const bf16* __restrict__ Bq,
                           const bf16* __restrict__ Bkv, const float* __restrict__ cosT,
                           const float* __restrict__ sinT, bf16* __restrict__ Qb,
                           bf16* __restrict__ KVb) {
    __shared__ alignas(16) bf16 As[2][128 * 32];
    __shared__ alignas(16) bf16 Bs[2][128 * 32];
    const int K = DIM;
    int tid = threadIdx.x;
    int lane = tid & 63, wave = tid >> 6;
    int wr = (wave >> 1) * 64, wc = (wave & 1) * 64;
    int id = blockIdx.x;
    int xcd = id & 7, rank = id >> 3;      // rank 0..127
    int by = xcd * 8 + (rank >> 4);        // 0..63
    int bxx = rank & 15;                   // 0..15 (virtual n block)
    int m0 = by * 128;
    bool isQ = (bxx < 8);
    const bf16* Bt = isQ ? Bq : Bkv;
    int n0 = (bxx & 7) * 128;
    int row = lane & 15, kk = (lane >> 4) * 8;
    int ch0 = wave * 128 + lane, ch1 = ch0 + 64;
    int r0 = ch0 >> 2, c0e = (ch0 & 3) * 8;
    int r1 = ch1 >> 2, c1e = (ch1 & 3) * 8;
    f32x4 acc[4][4] = {};
    gload16(&A[(size_t)(m0 + r0) * K + c0e], &As[0][wave * 1024]);
    gload16(&A[(size_t)(m0 + r1) * K + c1e], &As[0][wave * 1024 + 512]);
    gload16(&Bt[(size_t)(n0 + r0) * K + c0e], &Bs[0][wave * 1024]);
    gload16(&Bt[(size_t)(n0 + r1) * K + c1e], &Bs[0][wave * 1024 + 512]);
    __syncthreads();
    int cur = 0;
    for (int k0 = 0; k0 < K; k0 += 32) {
        int nxt = cur ^ 1;
        if (k0 + 32 < K) {
            gload16(&A[(size_t)(m0 + r0) * K + k0 + 32 + c0e], &As[nxt][wave * 1024]);
            gload16(&A[(size_t)(m0 + r1) * K + k0 + 32 + c1e], &As[nxt][wave * 1024 + 512]);
            gload16(&Bt[(size_t)(n0 + r0) * K + k0 + 32 + c0e], &Bs[nxt][wave * 1024]);
            gload16(&Bt[(size_t)(n0 + r1) * K + k0 + 32 + c1e], &Bs[nxt][wave * 1024 + 512]);
        }
        bf16x8 af[4], bfr[4];
#pragma unroll
        for (int mt = 0; mt < 4; ++mt) af[mt] = *(const bf16x8*)&As[cur][(wr + mt * 16 + row) * 32 + kk];
#pragma unroll
        for (int nt = 0; nt < 4; ++nt) bfr[nt] = *(const bf16x8*)&Bs[cur][(wc + nt * 16 + row) * 32 + kk];
#pragma unroll
        for (int mt = 0; mt < 4; ++mt)
#pragma unroll
            for (int nt = 0; nt < 4; ++nt)
                acc[mt][nt] = __builtin_amdgcn_mfma_f32_16x16x32_bf16(af[mt], bfr[nt], acc[mt][nt], 0, 0, 0);
        __syncthreads();
        cur = nxt;
    }
    // fused RoPE epilogue: cols e=nt*16+ocol (nt<2) pair with e+32 in acc[mt][nt+2]
    int orow = (lane >> 4) * 4, ocol = lane & 15;
    int head_g = (n0 + wc) >> 6;               // 0..15
    float sc = isQ ? QSCALE : 1.0f;
    bf16* Cb = isQ ? Qb : KVb;
#pragma unroll
    for (int mt = 0; mt < 4; ++mt) {
#pragma unroll
        for (int i = 0; i < 4; ++i) {
            int rowg = m0 + wr + mt * 16 + orow + i;
            int t = rowg & (NSEQ - 1), bidx = rowg >> 12;
            int cch = bidx * NH + head_g;
            size_t base = ((size_t)cch * NSEQ + t) * HD;
#pragma unroll
            for (int nt = 0; nt < 2; ++nt) {
                int e = nt * 16 + ocol;
                float x1 = acc[mt][nt][i], x2 = acc[mt][nt + 2][i];
                float cv = cosT[t * 32 + e], sv = sinT[t * 32 + e];
                Cb[base + e]      = __float2bfloat16((x1 * cv - x2 * sv) * sc);
                Cb[base + e + 32] = __float2bfloat16((x2 * cv + x1 * sv) * sc);
            }
        }
    }
}

// final GEMM: 2-phase dbuf, XCD swizzle, per-row-tile weight/bias select, fp32 out
__launch_bounds__(256, 2)
__global__ void k_gemm_out(const bf16* __restrict__ A, const bf16* __restrict__ Bt0,
                           const bf16* __restrict__ Bt1, const float* __restrict__ bias0,
                           const float* __restrict__ bias1, float* __restrict__ C) {
    __shared__ alignas(16) bf16 As[2][128 * 32];
    __shared__ alignas(16) bf16 Bs[2][128 * 32];
    const int K = DIM;
    int tid = threadIdx.x;
    int lane = tid & 63, wave = tid >> 6;
    int wr = (wave >> 1) * 64, wc = (wave & 1) * 64;
    int id = blockIdx.x;                   // 512 blocks
    int xcd = id & 7, rank = id >> 3;      // 0..63
    int by = xcd * 8 + (rank >> 3);        // 0..63
    int bx = rank & 7;
    int m0 = by * 128, n0 = bx * 128;
    bool first = (m0 & (NSEQ - 1)) < MSEG;
    const bf16* Bt = first ? Bt0 : Bt1;
    const float* bias = first ? bias0 : bias1;
    int row = lane & 15, kk = (lane >> 4) * 8;
    int ch0 = wave * 128 + lane, ch1 = ch0 + 64;
    int r0 = ch0 >> 2, c0e = (ch0 & 3) * 8;
    int r1 = ch1 >> 2, c1e = (ch1 & 3) * 8;
    f32x4 acc[4][4] = {};
    gload16(&A[(size_t)(m0 + r0) * K + c0e], &As[0][wave * 1024]);
    gload16(&A[(size_t)(m0 + r1) * K + c1e], &As[0][wave * 1024 + 512]);
    gload16(&Bt[(size_t)(n0 + r0) * K + c0e], &Bs[0][wave * 1024]);
    gload16(&Bt[(size_t)(n0 + r1) * K + c1e], &Bs[0][wave * 1024 + 512]);
    __syncthreads();
    int cur = 0;
    for (int k0 = 0; k0 < K; k0 += 32) {
        int nxt = cur ^ 1;
        if (k0 + 32 < K) {
            gload16(&A[(size_t)(m0 + r0) * K + k0 + 32 + c0e], &As[nxt][wave * 1024]);
            gload16(&A[(size_t)(m0 + r1) * K + k0 + 32 + c1e], &As[nxt][wave * 1024 + 512]);
            gload16(&Bt[(size_t)(n0 + r0) * K + k0 + 32 + c0e], &Bs[nxt][wave * 1024]);
            gload16(&Bt[(size_t)(n0 + r1) * K + k0 + 32 + c1e], &Bs[nxt][wave * 1024 + 512]);
        }
        bf16x8 af[4], bfr[4];
#pragma unroll
        for (int mt = 0; mt < 4; ++mt) af[mt] = *(const bf16x8*)&As[cur][(wr + mt * 16 + row) * 32 + kk];
#pragma unroll
        for (int nt = 0; nt < 4; ++nt) bfr[nt] = *(const bf16x8*)&Bs[cur][(wc + nt * 16 + row) * 32 + kk];
#pragma unroll
        for (int mt = 0; mt < 4; ++mt)
#pragma unroll
            for (int nt = 0; nt < 4; ++nt)
                acc[mt][nt] = __builtin_amdgcn_mfma_f32_16x16x32_bf16(af[mt], bfr[nt], acc[mt][nt], 0, 0, 0);
        __syncthreads();
        cur = nxt;
    }
    int orow = (lane >> 4) * 4, ocol = lane & 15;
#pragma unroll
    for (int mt = 0; mt < 4; ++mt)
#pragma unroll
        for (int nt = 0; nt < 4; ++nt) {
            float bv = bias[n0 + wc + nt * 16 + ocol];
#pragma unroll
            for (int i = 0; i < 4; ++i)
                C[(size_t)(m0 + wr + mt * 16 + orow + i) * DIM + n0 + wc + nt * 16 + ocol] = acc[mt][nt][i] + bv;
        }
}

// --------------- K/V fragment pre-pack: KVf[c][tile][frag 0-7][lane][8]
__global__ void k_pack(const bf16* __restrict__ KVb, bf16* __restrict__ KVf) {
    __shared__ bf16 T[256][72];
    int c = blockIdx.y, t0 = blockIdx.x * 256;
    int tid = threadIdx.x;
    int r = tid >> 3, cc = (tid & 7) * 8;
#pragma unroll
    for (int it = 0; it < 8; ++it) {
        int row = it * 32 + r;
        *(bf16x8*)&T[row][cc] = *(const bf16x8*)&KVb[((size_t)c * NSEQ + t0 + row) * HD + cc];
    }
    __syncthreads();
    int lane = tid & 63, wave = tid >> 6;
    int hi = lane >> 5, lq = lane & 31;
    size_t base = (((size_t)c * 128 + (t0 >> 5)) * 8) * 512;   // elements
    for (int tl = wave * 2; tl < wave * 2 + 2; ++tl) {
        size_t tb = base + (size_t)tl * 4096;
#pragma unroll
        for (int f = 0; f < 4; ++f) {
            bf16x8 v = *(const bf16x8*)&T[tl * 32 + lq][f * 16 + hi * 8];
            *(bf16x8*)&KVf[tb + (size_t)f * 512 + lane * 8] = v;
        }
#pragma unroll
        for (int m = 0; m < 4; ++m) {
            int d0 = (m >> 1) * 32, sub = m & 1;
            union { bf16 h[8]; bf16x8 v; } pk;
#pragma unroll
            for (int j = 0; j < 8; ++j)
                pk.h[j] = T[tl * 32 + sub * 16 + hi * 8 + j][d0 + lq];
            *(bf16x8*)&KVf[tb + (size_t)(4 + m) * 512 + lane * 8] = pk.v;
        }
    }
}

// ---------------------------------------------------------------- attention (swapped-QK 32x32)
// Software-pipelined: softmax(i) consumes scores computed LAST iteration; QK(i+1) issued
// after exp frees the score registers. QK MFMA latency and K/V load latency both get a
// full iteration of slack -> critical chain = softmax+pack only.
__launch_bounds__(256, 4)
__global__ void k_attn(const bf16* __restrict__ Qb, const bf16* __restrict__ KVf,
                       bf16* __restrict__ Ob) {
    int lane = threadIdx.x & 63, wave = threadIdx.x >> 6;
    int hi = lane >> 5, lq = lane & 31;
    int id = blockIdx.x;
    int xcd = id & 7, rank = id >> 3;           // rank 0..127
    int c = xcd * 4 + (rank & 3);
    int hr = rank >> 2;                         // 0..31, heavy-first
    int bx, seg;
    if (hr < 28) { bx = 3 - hr / 7; seg = 1 + hr % 7; }
    else         { seg = 0; bx = 31 - hr; }
    int i0 = bx * 128 + wave * 32;              // q-row offset within segment
    int bidx = c >> 4, head = c & 15;
    int tq = seg * MSEG + i0 + lq;
    const bf16* qptr = &Qb[((size_t)c * NSEQ + tq) * HD + hi * 8];
    bf16x8 qf[4];
#pragma unroll
    for (int dc = 0; dc < 4; ++dc) qf[dc] = *(const bf16x8*)&qptr[dc * 16];
    f32x16 o0 = {}, o1 = {};
    float mrun = -FLT_MAX, lrun = 0.f;
    int kvbase = (seg == 0) ? 0 : (seg - 1) * MSEG;
    int cstart = (seg == 0) ? 0 : MSEG;
    int cend = cstart + i0 + 32;
    int nT = cend >> 5;                         // number of 32-kv tiles

    const bf16* fb = &KVf[((size_t)c * 128 + (kvbase >> 5)) * 4096 + lane * 8];

    // ---- prologue: s = QK(tile 0); ka = K(tile 1)
    bf16x8 ka0, ka1, ka2, ka3;
    f32x16 s;
    {
        bf16x8 k0 = *(const bf16x8*)&fb[0];
        bf16x8 k1 = *(const bf16x8*)&fb[512];
        bf16x8 k2 = *(const bf16x8*)&fb[1024];
        bf16x8 k3 = *(const bf16x8*)&fb[1536];
        if (nT > 1) {
            const bf16* p1 = fb + 4096;
            ka0 = *(const bf16x8*)&p1[0];
            ka1 = *(const bf16x8*)&p1[512];
            ka2 = *(const bf16x8*)&p1[1024];
            ka3 = *(const bf16x8*)&p1[1536];
        }
        f32x16 z = {};
        __builtin_amdgcn_s_setprio(1);
        z = __builtin_amdgcn_mfma_f32_32x32x16_bf16(k0, qf[0], z, 0, 0, 0);
        z = __builtin_amdgcn_mfma_f32_32x32x16_bf16(k1, qf[1], z, 0, 0, 0);
        z = __builtin_amdgcn_mfma_f32_32x32x16_bf16(k2, qf[2], z, 0, 0, 0);
        z = __builtin_amdgcn_mfma_f32_32x32x16_bf16(k3, qf[3], z, 0, 0, 0);
        __builtin_amdgcn_s_setprio(0);
        s = z;
    }

    for (int it = 0; it < nT; ++it) {
        int c0 = it * 32;
        // ---- V for this tile (consumed at the end; softmax+QK hide its latency)
        const bf16* pv = fb + (size_t)it * 4096 + 2048;
        bf16x8 vf0 = *(const bf16x8*)&pv[0];
        bf16x8 vf1 = *(const bf16x8*)&pv[512];
        bf16x8 vf2 = *(const bf16x8*)&pv[1024];
        bf16x8 vf3 = *(const bf16x8*)&pv[1536];
        // ---- causal mask on s (tile it; boundary tiles only)
        if (c0 + 31 >= cstart && c0 + 31 - cstart > i0) {
#pragma unroll
            for (int r = 0; r < 16; ++r) {
                int kvg = c0 + ((r & 3) + 8 * (r >> 2) + 4 * hi);
                if (kvg >= cstart && kvg - cstart > i0 + lq) s[r] = -FLT_MAX;
            }
        }
        // ---- online softmax (base-2), defer-max
        float m8[8], m4[4];
#pragma unroll
        for (int r = 0; r < 8; ++r) m8[r] = fmaxf(s[2 * r], s[2 * r + 1]);
#pragma unroll
        for (int r = 0; r < 4; ++r) m4[r] = fmaxf(m8[2 * r], m8[2 * r + 1]);
        float vmax = fmaxf(fmaxf(m4[0], m4[1]), fmaxf(m4[2], m4[3]));
        vmax = fmaxf(vmax, __shfl_xor(vmax, 32));
        if (__any(vmax > mrun + 11.5f)) {
            float nm = fmaxf(mrun, vmax);
            float al = fast_exp2(mrun - nm);
#pragma unroll
            for (int r = 0; r < 16; ++r) { o0[r] *= al; o1[r] *= al; }
            lrun *= al;
            mrun = nm;
        }
        float p[16];
#pragma unroll
        for (int r = 0; r < 16; ++r) p[r] = fast_exp2(s[r] - mrun);   // s dead after this
        // ---- QK for tile it+1 into the freed score registers; reload ka with K(it+2)
        if (it + 1 < nT) {
            f32x16 z = {};
            __builtin_amdgcn_s_setprio(1);
            z = __builtin_amdgcn_mfma_f32_32x32x16_bf16(ka0, qf[0], z, 0, 0, 0);
            z = __builtin_amdgcn_mfma_f32_32x32x16_bf16(ka1, qf[1], z, 0, 0, 0);
            z = __builtin_amdgcn_mfma_f32_32x32x16_bf16(ka2, qf[2], z, 0, 0, 0);
            z = __builtin_amdgcn_mfma_f32_32x32x16_bf16(ka3, qf[3], z, 0, 0, 0);
            __builtin_amdgcn_s_setprio(0);
            s = z;
            if (it + 2 < nT) {
                const bf16* pn = fb + (size_t)(it + 2) * 4096;
                ka0 = *(const bf16x8*)&pn[0];
                ka1 = *(const bf16x8*)&pn[512];
                ka2 = *(const bf16x8*)&pn[1024];
                ka3 = *(const bf16x8*)&pn[1536];
            }
        }
        // ---- sum + pack (critical path continues from p)
        float a8[8], a4[4];
#pragma unroll
        for (int r = 0; r < 8; ++r) a8[r] = p[2 * r] + p[2 * r + 1];
#pragma unroll
        for (int r = 0; r < 4; ++r) a4[r] = a8[2 * r] + a8[2 * r + 1];
        lrun += (a4[0] + a4[1]) + (a4[2] + a4[3]);
        unsigned pk[8];
#pragma unroll
        for (int k = 0; k < 8; ++k) {
            union { bf16 h[2]; unsigned u; } cv;
            cv.h[0] = __float2bfloat16(p[2 * k]);
            cv.h[1] = __float2bfloat16(p[2 * k + 1]);
            pk[k] = cv.u;
        }
        unsigned u0 = hi ? pk[0] : pk[2];
        unsigned u1 = hi ? pk[1] : pk[3];
        unsigned u2 = hi ? pk[4] : pk[6];
        unsigned u3 = hi ? pk[5] : pk[7];
        unsigned w0 = (unsigned)__shfl_xor((int)u0, 32);
        unsigned w1 = (unsigned)__shfl_xor((int)u1, 32);
        unsigned w2 = (unsigned)__shfl_xor((int)u2, 32);
        unsigned w3 = (unsigned)__shfl_xor((int)u3, 32);
        union { unsigned u[4]; bf16x8 v; } b0, b1;
        b0.u[0] = hi ? w0 : pk[0];
        b0.u[1] = hi ? w1 : pk[1];
        b0.u[2] = hi ? pk[2] : w0;
        b0.u[3] = hi ? pk[3] : w1;
        b1.u[0] = hi ? w2 : pk[4];
        b1.u[1] = hi ? w3 : pk[5];
        b1.u[2] = hi ? pk[6] : w2;
        b1.u[3] = hi ? pk[7] : w3;
        // ---- O^T[d][q] += V^T P^T
        __builtin_amdgcn_s_setprio(1);
        o0 = __builtin_amdgcn_mfma_f32_32x32x16_bf16(vf0, b0.v, o0, 0, 0, 0);
        o1 = __builtin_amdgcn_mfma_f32_32x32x16_bf16(vf2, b0.v, o1, 0, 0, 0);
        o0 = __builtin_amdgcn_mfma_f32_32x32x16_bf16(vf1, b1.v, o0, 0, 0, 0);
        o1 = __builtin_amdgcn_mfma_f32_32x32x16_bf16(vf3, b1.v, o1, 0, 0, 0);
        __builtin_amdgcn_s_setprio(0);
    }
    lrun += __shfl_xor(lrun, 32);
    float inv = 1.0f / lrun;
    size_t obase = ((size_t)bidx * NSEQ + tq) * DIM + head * HD;
#pragma unroll
    for (int dt = 0; dt < 2; ++dt)
#pragma unroll
        for (int a = 0; a < 4; ++a) {
            union { bf16 h[4]; uint2 u; } pkd;
            const f32x16& ov = dt ? o1 : o0;
#pragma unroll
            for (int i = 0; i < 4; ++i) pkd.h[i] = __float2bfloat16(ov[4 * a + i] * inv);
            *(uint2*)&Ob[obase + dt * 32 + 8 * a + 4 * hi] = pkd.u;
        }
}

// ---------------------------------------------------------------- launch
extern "C" void kernel_launch(void* const* d_in, const int* in_sizes, int n_in,
                              void* d_out, int out_size, void* d_ws, size_t ws_size,
                              hipStream_t stream) {
    const float* x   = (const float*)d_in[0];
    const float* Wq  = (const float*)d_in[1];
    const float* Wkv = (const float*)d_in[2];
    const float* Wo  = (const float*)d_in[3];
    const float* bo  = (const float*)d_in[4];
    const float* Wo0 = (const float*)d_in[5];
    const float* bo0 = (const float*)d_in[6];
    float* out = (float*)d_out;

    char* ws = (char*)d_ws;
    size_t off = 0;
    auto alloc = [&](size_t bytes) { void* p = ws + off; off += (bytes + 255) & ~(size_t)255; return p; };
    float* cosT = (float*)alloc((size_t)NSEQ * 32 * 4);
    float* sinT = (float*)alloc((size_t)NSEQ * 32 * 4);
    bf16* Xb    = (bf16*)alloc((size_t)ROWS * DIM * 2);
    bf16* WqT   = (bf16*)alloc((size_t)DIM * DIM * 2);
    bf16* WkvT  = (bf16*)alloc((size_t)DIM * DIM * 2);
    bf16* WoT   = (bf16*)alloc((size_t)DIM * DIM * 2);
    bf16* Wo0T  = (bf16*)alloc((size_t)DIM * DIM * 2);
    bf16* Qb    = (bf16*)alloc((size_t)NC * NSEQ * HD * 2);
    bf16* KVb   = (bf16*)alloc((size_t)NC * NSEQ * HD * 2);
    bf16* KVf   = (bf16*)alloc((size_t)NC * 128 * 4096 * 2);
    bf16* Ob    = (bf16*)alloc((size_t)ROWS * DIM * 2);

    hipLaunchKernelGGL(k_rope_tab, dim3(NSEQ * 32 / 256), dim3(256), 0, stream, cosT, sinT);
    hipLaunchKernelGGL(k_convert_x, dim3(ROWS * DIM / 4 / 256), dim3(256), 0, stream, x, Xb);
    hipLaunchKernelGGL(k_transpose, dim3(32, 32), dim3(32, 8), 0, stream, Wq, WqT);
    hipLaunchKernelGGL(k_transpose, dim3(32, 32), dim3(32, 8), 0, stream, Wkv, WkvT);
    hipLaunchKernelGGL(k_transpose, dim3(32, 32), dim3(32, 8), 0, stream, Wo, WoT);
    hipLaunchKernelGGL(k_transpose, dim3(32, 32), dim3(32, 8), 0, stream, Wo0, Wo0T);

    hipLaunchKernelGGL(k_gemm_qkv, dim3(1024), dim3(256), 0, stream, Xb, WqT, WkvT, cosT, sinT, Qb, KVb);
    hipLaunchKernelGGL(k_pack, dim3(16, 32), dim3(256), 0, stream, KVb, KVf);

    hipLaunchKernelGGL(k_attn, dim3(1024), dim3(256), 0, stream, Qb, KVf, Ob);

    hipLaunchKernelGGL(k_gemm_out, dim3(512), dim3(256), 0, stream, Ob, Wo0T, WoT, bo0, bo, out);
}

// Round 11
// 158.247 us; speedup vs baseline: 2.2700x; 1.0197x over previous
//
#include <hip/hip_runtime.h>
#include <hip/hip_bf16.h>
#include <float.h>

using bf16 = __hip_bfloat16;
typedef __attribute__((ext_vector_type(8))) short bf16x8;
typedef __attribute__((ext_vector_type(4))) float f32x4;
typedef __attribute__((ext_vector_type(16))) float f32x16;

#define DIM   1024
#define NSEQ  4096
#define BATCH 2
#define NH    16
#define HD    64
#define NSEG  8
#define MSEG  512
#define ROWS  (BATCH*NSEQ)   // 8192
#define NC    (BATCH*NH)     // 32
#define QSCALE (0.125f * 1.44269504f)   // d^-0.5 * log2(e)  (exp2 softmax)

__device__ __forceinline__ float fast_exp2(float x) {
    float r;
    asm volatile("v_exp_f32 %0, %1" : "=v"(r) : "v"(x));
    return r;
}

__device__ __forceinline__ void gload16(const bf16* g, bf16* l) {
    __builtin_amdgcn_global_load_lds((const __attribute__((address_space(1))) unsigned int*)g,
                                     (__attribute__((address_space(3))) unsigned int*)l, 16, 0, 0);
}

// ---------------------------------------------------------------- rope table
__global__ void k_rope_tab(float* __restrict__ cosT, float* __restrict__ sinT) {
    int idx = blockIdx.x * 256 + threadIdx.x;     // 4096*32 = 131072
    int t = idx >> 5, i = idx & 31;
    float freq = 1.0f / powf(10000.0f, (float)(2 * i) * (1.0f / 64.0f));
    float a = (float)t * freq;
    cosT[idx] = cosf(a);
    sinT[idx] = sinf(a);
}

// ---------------------------------------------------------------- x -> bf16
__global__ void k_convert_x(const float* __restrict__ X, bf16* __restrict__ Xb) {
    int i = (blockIdx.x * 256 + threadIdx.x) * 4;
    float4 v = *(const float4*)&X[i];
    union { bf16 h[4]; uint2 u; } p;
    p.h[0] = __float2bfloat16(v.x);
    p.h[1] = __float2bfloat16(v.y);
    p.h[2] = __float2bfloat16(v.z);
    p.h[3] = __float2bfloat16(v.w);
    *(uint2*)&Xb[i] = p.u;
}

// ------------------------------------------- W[k][n] -> Wt[n][k] (bf16)
__global__ void k_transpose(const float* __restrict__ W, bf16* __restrict__ Wt) {
    __shared__ float tile[32][33];
    int bx = blockIdx.x * 32;   // n
    int by = blockIdx.y * 32;   // k
    int tx = threadIdx.x;
    for (int i = threadIdx.y; i < 32; i += 8)
        tile[i][tx] = W[(size_t)(by + i) * DIM + bx + tx];
    __syncthreads();
    for (int i = threadIdx.y; i < 32; i += 8)
        Wt[(size_t)(bx + i) * DIM + by + tx] = __float2bfloat16(tile[tx][i]);
}

// --------------- merged Q+KV projection GEMM, 2-phase dbuf, FUSED RoPE epilogue
// Q blocks: rope -> LDS bounce -> coalesced Qb[c][t][d] stores.
// KV blocks: rope -> LDS bounce -> DIRECT KVf fragment emission (k_pack fused away).
__launch_bounds__(256, 4)
__global__ void k_gemm_qkv(const bf16* __restrict__ A, const bf16* __restrict__ Bq,
                           const bf16* __restrict__ Bkv, const float* __restrict__ cosT,
                           const float* __restrict__ sinT, bf16* __restrict__ Qb,
                           bf16* __restrict__ KVf) {
    __shared__ alignas(16) bf16 SH[18432];        // 36.9KB: As(8192) Bs(8192) in-loop; 4x(64x72) bounce
    bf16* AsB = SH;                               // [2][4096]
    bf16* BsB = SH + 8192;                        // [2][4096]
    const int K = DIM;
    int tid = threadIdx.x;
    int lane = tid & 63, wave = tid >> 6;
    int hi = lane >> 5, lq = lane & 31;
    int wr = (wave >> 1) * 64, wc = (wave & 1) * 64;
    int id = blockIdx.x;
    int xcd = id & 7, rank = id >> 3;      // rank 0..127
    int by = xcd * 8 + (rank >> 4);        // 0..63
    int bxx = rank & 15;                   // 0..15 (virtual n block)
    int m0 = by * 128;
    bool isQ = (bxx < 8);
    const bf16* Bt = isQ ? Bq : Bkv;
    int n0 = (bxx & 7) * 128;
    int row = lane & 15, kk = (lane >> 4) * 8;
    int ch0 = wave * 128 + lane, ch1 = ch0 + 64;
    int r0 = ch0 >> 2, c0e = (ch0 & 3) * 8;
    int r1 = ch1 >> 2, c1e = (ch1 & 3) * 8;
    f32x4 acc[4][4] = {};
    gload16(&A[(size_t)(m0 + r0) * K + c0e], &AsB[wave * 1024]);
    gload16(&A[(size_t)(m0 + r1) * K + c1e], &AsB[wave * 1024 + 512]);
    gload16(&Bt[(size_t)(n0 + r0) * K + c0e], &BsB[wave * 1024]);
    gload16(&Bt[(size_t)(n0 + r1) * K + c1e], &BsB[wave * 1024 + 512]);
    __syncthreads();
    int cur = 0;
    for (int k0 = 0; k0 < K; k0 += 32) {
        int nxt = cur ^ 1;
        if (k0 + 32 < K) {
            gload16(&A[(size_t)(m0 + r0) * K + k0 + 32 + c0e], &AsB[nxt * 4096 + wave * 1024]);
            gload16(&A[(size_t)(m0 + r1) * K + k0 + 32 + c1e], &AsB[nxt * 4096 + wave * 1024 + 512]);
            gload16(&Bt[(size_t)(n0 + r0) * K + k0 + 32 + c0e], &BsB[nxt * 4096 + wave * 1024]);
            gload16(&Bt[(size_t)(n0 + r1) * K + k0 + 32 + c1e], &BsB[nxt * 4096 + wave * 1024 + 512]);
        }
        bf16x8 af[4], bfr[4];
#pragma unroll
        for (int mt = 0; mt < 4; ++mt) af[mt] = *(const bf16x8*)&AsB[cur * 4096 + (wr + mt * 16 + row) * 32 + kk];
#pragma unroll
        for (int nt = 0; nt < 4; ++nt) bfr[nt] = *(const bf16x8*)&BsB[cur * 4096 + (wc + nt * 16 + row) * 32 + kk];
#pragma unroll
        for (int mt = 0; mt < 4; ++mt)
#pragma unroll
            for (int nt = 0; nt < 4; ++nt)
                acc[mt][nt] = __builtin_amdgcn_mfma_f32_16x16x32_bf16(af[mt], bfr[nt], acc[mt][nt], 0, 0, 0);
        __syncthreads();
        cur = nxt;
    }
    // ---- epilogue: rope into per-wave LDS bounce region (rows 0..63 x d 0..63, stride 72)
    bf16* Tw = SH + wave * (64 * 72);
    int orow = (lane >> 4) * 4, ocol = lane & 15;
    int head_g = (n0 + wc) >> 6;               // 0..15
    float sc = isQ ? QSCALE : 1.0f;
    int bidx = (m0 + wr) >> 12;
    int tbase = (m0 + wr) & (NSEQ - 1);
    int cch = bidx * NH + head_g;
#pragma unroll
    for (int mt = 0; mt < 4; ++mt) {
#pragma unroll
        for (int i = 0; i < 4; ++i) {
            int rl = mt * 16 + orow + i;
            int t = tbase + rl;
#pragma unroll
            for (int nt = 0; nt < 2; ++nt) {
                int e = nt * 16 + ocol;
                float x1 = acc[mt][nt][i], x2 = acc[mt][nt + 2][i];
                float cv = cosT[t * 32 + e], sv = sinT[t * 32 + e];
                Tw[rl * 72 + e]      = __float2bfloat16((x1 * cv - x2 * sv) * sc);
                Tw[rl * 72 + e + 32] = __float2bfloat16((x2 * cv + x1 * sv) * sc);
            }
        }
    }
    if (isQ) {
        // coalesced Qb[c][t][d] stores: 8 rows x 128B = 1KB contiguous per wave-instr
        int rsub = lane >> 3, dg = (lane & 7) * 8;
        size_t qbase = ((size_t)cch * NSEQ + tbase) * HD;
#pragma unroll
        for (int rr = 0; rr < 8; ++rr) {
            int rl = rr * 8 + rsub;
            *(uint4*)&Qb[qbase + (size_t)rl * HD + dg] = *(const uint4*)&Tw[rl * 72 + dg];
        }
    } else {
        // direct KVf fragment emission: 2 tiles of 32 rows each
        size_t kvfbase = ((size_t)cch * 128 + (tbase >> 5)) * 4096;   // elements
#pragma unroll
        for (int st = 0; st < 2; ++st) {
            size_t tb = kvfbase + (size_t)st * 4096;
#pragma unroll
            for (int f = 0; f < 4; ++f)
                *(uint4*)&KVf[tb + f * 512 + lane * 8] =
                    *(const uint4*)&Tw[(st * 32 + lq) * 72 + f * 16 + hi * 8];
#pragma unroll
            for (int m = 0; m < 4; ++m) {
                int d0 = (m >> 1) * 32, sb = m & 1;
                union { bf16 h[8]; uint4 u; } pk;
#pragma unroll
                for (int j = 0; j < 8; ++j)
                    pk.h[j] = Tw[(st * 32 + sb * 16 + hi * 8 + j) * 72 + d0 + lq];
                *(uint4*)&KVf[tb + (size_t)(4 + m) * 512 + lane * 8] = pk.u;
            }
        }
    }
}

// final GEMM: 128x64 tile, 1024 blocks (4/CU), 2-phase dbuf, XCD swizzle, fp32 out
__launch_bounds__(256, 4)
__global__ void k_gemm_out(const bf16* __restrict__ A, const bf16* __restrict__ Bt0,
                           const bf16* __restrict__ Bt1, const float* __restrict__ bias0,
                           const float* __restrict__ bias1, float* __restrict__ C) {
    __shared__ alignas(16) bf16 As[2][128 * 32];
    __shared__ alignas(16) bf16 Bs[2][64 * 32];
    const int K = DIM;
    int tid = threadIdx.x;
    int lane = tid & 63, wave = tid >> 6;
    int wr = (wave >> 1) * 64, wc = (wave & 1) * 32;
    int id = blockIdx.x;                   // 1024 blocks
    int xcd = id & 7, rank = id >> 3;      // 0..127
    int by = xcd * 8 + (rank >> 4);        // 0..63
    int bx = rank & 15;                    // 0..15
    int m0 = by * 128, n0 = bx * 64;
    bool first = (m0 & (NSEQ - 1)) < MSEG;
    const bf16* Bt = first ? Bt0 : Bt1;
    const float* bias = first ? bias0 : bias1;
    int row = lane & 15, kk = (lane >> 4) * 8;
    int ch0 = wave * 128 + lane, ch1 = ch0 + 64;
    int r0 = ch0 >> 2, c0e = (ch0 & 3) * 8;
    int r1 = ch1 >> 2, c1e = (ch1 & 3) * 8;
    int cb = wave * 64 + lane;
    int rb = cb >> 2, cbe = (cb & 3) * 8;
    f32x4 acc[4][2] = {};
    gload16(&A[(size_t)(m0 + r0) * K + c0e], &As[0][wave * 1024]);
    gload16(&A[(size_t)(m0 + r1) * K + c1e], &As[0][wave * 1024 + 512]);
    gload16(&Bt[(size_t)(n0 + rb) * K + cbe], &Bs[0][wave * 512]);
    __syncthreads();
    int cur = 0;
    for (int k0 = 0; k0 < K; k0 += 32) {
        int nxt = cur ^ 1;
        if (k0 + 32 < K) {
            gload16(&A[(size_t)(m0 + r0) * K + k0 + 32 + c0e], &As[nxt][wave * 1024]);
            gload16(&A[(size_t)(m0 + r1) * K + k0 + 32 + c1e], &As[nxt][wave * 1024 + 512]);
            gload16(&Bt[(size_t)(n0 + rb) * K + k0 + 32 + cbe], &Bs[nxt][wave * 512]);
        }
        bf16x8 af[4], bfr[2];
#pragma unroll
        for (int mt = 0; mt < 4; ++mt) af[mt] = *(const bf16x8*)&As[cur][(wr + mt * 16 + row) * 32 + kk];
#pragma unroll
        for (int nt = 0; nt < 2; ++nt) bfr[nt] = *(const bf16x8*)&Bs[cur][(wc + nt * 16 + row) * 32 + kk];
#pragma unroll
        for (int mt = 0; mt < 4; ++mt)
#pragma unroll
            for (int nt = 0; nt < 2; ++nt)
                acc[mt][nt] = __builtin_amdgcn_mfma_f32_16x16x32_bf16(af[mt], bfr[nt], acc[mt][nt], 0, 0, 0);
        __syncthreads();
        cur = nxt;
    }
    int orow = (lane >> 4) * 4, ocol = lane & 15;
#pragma unroll
    for (int mt = 0; mt < 4; ++mt)
#pragma unroll
        for (int nt = 0; nt < 2; ++nt) {
            float bv = bias[n0 + wc + nt * 16 + ocol];
#pragma unroll
            for (int i = 0; i < 4; ++i)
                C[(size_t)(m0 + wr + mt * 16 + orow + i) * DIM + n0 + wc + nt * 16 + ocol] = acc[mt][nt][i] + bv;
        }
}

// ---------------------------------------------------------------- attention (swapped-QK 32x32)
// Software-pipelined: softmax(i) consumes scores computed LAST iteration; QK(i+1) issued
// after exp frees the score registers. (unchanged from R10)
__launch_bounds__(256, 4)
__global__ void k_attn(const bf16* __restrict__ Qb, const bf16* __restrict__ KVf,
                       bf16* __restrict__ Ob) {
    int lane = threadIdx.x & 63, wave = threadIdx.x >> 6;
    int hi = lane >> 5, lq = lane & 31;
    int id = blockIdx.x;
    int xcd = id & 7, rank = id >> 3;           // rank 0..127
    int c = xcd * 4 + (rank & 3);
    int hr = rank >> 2;                         // 0..31, heavy-first
    int bx, seg;
    if (hr < 28) { bx = 3 - hr / 7; seg = 1 + hr % 7; }
    else         { seg = 0; bx = 31 - hr; }
    int i0 = bx * 128 + wave * 32;              // q-row offset within segment
    int bidx = c >> 4, head = c & 15;
    int tq = seg * MSEG + i0 + lq;
    const bf16* qptr = &Qb[((size_t)c * NSEQ + tq) * HD + hi * 8];
    bf16x8 qf[4];
#pragma unroll
    for (int dc = 0; dc < 4; ++dc) qf[dc] = *(const bf16x8*)&qptr[dc * 16];
    f32x16 o0 = {}, o1 = {};
    float mrun = -FLT_MAX, lrun = 0.f;
    int kvbase = (seg == 0) ? 0 : (seg - 1) * MSEG;
    int cstart = (seg == 0) ? 0 : MSEG;
    int cend = cstart + i0 + 32;
    int nT = cend >> 5;                         // number of 32-kv tiles

    const bf16* fb = &KVf[((size_t)c * 128 + (kvbase >> 5)) * 4096 + lane * 8];

    // ---- prologue: s = QK(tile 0); ka = K(tile 1)
    bf16x8 ka0, ka1, ka2, ka3;
    f32x16 s;
    {
        bf16x8 k0 = *(const bf16x8*)&fb[0];
        bf16x8 k1 = *(const bf16x8*)&fb[512];
        bf16x8 k2 = *(const bf16x8*)&fb[1024];
        bf16x8 k3 = *(const bf16x8*)&fb[1536];
        if (nT > 1) {
            const bf16* p1 = fb + 4096;
            ka0 = *(const bf16x8*)&p1[0];
            ka1 = *(const bf16x8*)&p1[512];
            ka2 = *(const bf16x8*)&p1[1024];
            ka3 = *(const bf16x8*)&p1[1536];
        }
        f32x16 z = {};
        __builtin_amdgcn_s_setprio(1);
        z = __builtin_amdgcn_mfma_f32_32x32x16_bf16(k0, qf[0], z, 0, 0, 0);
        z = __builtin_amdgcn_mfma_f32_32x32x16_bf16(k1, qf[1], z, 0, 0, 0);
        z = __builtin_amdgcn_mfma_f32_32x32x16_bf16(k2, qf[2], z, 0, 0, 0);
        z = __builtin_amdgcn_mfma_f32_32x32x16_bf16(k3, qf[3], z, 0, 0, 0);
        __builtin_amdgcn_s_setprio(0);
        s = z;
    }

    for (int it = 0; it < nT; ++it) {
        int c0 = it * 32;
        const bf16* pv = fb + (size_t)it * 4096 + 2048;
        bf16x8 vf0 = *(const bf16x8*)&pv[0];
        bf16x8 vf1 = *(const bf16x8*)&pv[512];
        bf16x8 vf2 = *(const bf16x8*)&pv[1024];
        bf16x8 vf3 = *(const bf16x8*)&pv[1536];
        if (c0 + 31 >= cstart && c0 + 31 - cstart > i0) {
#pragma unroll
            for (int r = 0; r < 16; ++r) {
                int kvg = c0 + ((r & 3) + 8 * (r >> 2) + 4 * hi);
                if (kvg >= cstart && kvg - cstart > i0 + lq) s[r] = -FLT_MAX;
            }
        }
        float m8[8], m4[4];
#pragma unroll
        for (int r = 0; r < 8; ++r) m8[r] = fmaxf(s[2 * r], s[2 * r + 1]);
#pragma unroll
        for (int r = 0; r < 4; ++r) m4[r] = fmaxf(m8[2 * r], m8[2 * r + 1]);
        float vmax = fmaxf(fmaxf(m4[0], m4[1]), fmaxf(m4[2], m4[3]));
        vmax = fmaxf(vmax, __shfl_xor(vmax, 32));
        if (__any(vmax > mrun + 11.5f)) {
            float nm = fmaxf(mrun, vmax);
            float al = fast_exp2(mrun - nm);
#pragma unroll
            for (int r = 0; r < 16; ++r) { o0[r] *= al; o1[r] *= al; }
            lrun *= al;
            mrun = nm;
        }
        float p[16];
#pragma unroll
        for (int r = 0; r < 16; ++r) p[r] = fast_exp2(s[r] - mrun);   // s dead after this
        if (it + 1 < nT) {
            f32x16 z = {};
            __builtin_amdgcn_s_setprio(1);
            z = __builtin_amdgcn_mfma_f32_32x32x16_bf16(ka0, qf[0], z, 0, 0, 0);
            z = __builtin_amdgcn_mfma_f32_32x32x16_bf16(ka1, qf[1], z, 0, 0, 0);
            z = __builtin_amdgcn_mfma_f32_32x32x16_bf16(ka2, qf[2], z, 0, 0, 0);
            z = __builtin_amdgcn_mfma_f32_32x32x16_bf16(ka3, qf[3], z, 0, 0, 0);
            __builtin_amdgcn_s_setprio(0);
            s = z;
            if (it + 2 < nT) {
                const bf16* pn = fb + (size_t)(it + 2) * 4096;
                ka0 = *(const bf16x8*)&pn[0];
                ka1 = *(const bf16x8*)&pn[512];
                ka2 = *(const bf16x8*)&pn[1024];
                ka3 = *(const bf16x8*)&pn[1536];
            }
        }
        float a8[8], a4[4];
#pragma unroll
        for (int r = 0; r < 8; ++r) a8[r] = p[2 * r] + p[2 * r + 1];
#pragma unroll
        for (int r = 0; r < 4; ++r) a4[r] = a8[2 * r] + a8[2 * r + 1];
        lrun += (a4[0] + a4[1]) + (a4[2] + a4[3]);
        unsigned pk[8];
#pragma unroll
        for (int k = 0; k < 8; ++k) {
            union { bf16 h[2]; unsigned u; } cv;
            cv.h[0] = __float2bfloat16(p[2 * k]);
            cv.h[1] = __float2bfloat16(p[2 * k + 1]);
            pk[k] = cv.u;
        }
        unsigned u0 = hi ? pk[0] : pk[2];
        unsigned u1 = hi ? pk[1] : pk[3];
        unsigned u2 = hi ? pk[4] : pk[6];
        unsigned u3 = hi ? pk[5] : pk[7];
        unsigned w0 = (unsigned)__shfl_xor((int)u0, 32);
        unsigned w1 = (unsigned)__shfl_xor((int)u1, 32);
        unsigned w2 = (unsigned)__shfl_xor((int)u2, 32);
        unsigned w3 = (unsigned)__shfl_xor((int)u3, 32);
        union { unsigned u[4]; bf16x8 v; } b0, b1;
        b0.u[0] = hi ? w0 : pk[0];
        b0.u[1] = hi ? w1 : pk[1];
        b0.u[2] = hi ? pk[2] : w0;
        b0.u[3] = hi ? pk[3] : w1;
        b1.u[0] = hi ? w2 : pk[4];
        b1.u[1] = hi ? w3 : pk[5];
        b1.u[2] = hi ? pk[6] : w2;
        b1.u[3] = hi ? pk[7] : w3;
        __builtin_amdgcn_s_setprio(1);
        o0 = __builtin_amdgcn_mfma_f32_32x32x16_bf16(vf0, b0.v, o0, 0, 0, 0);
        o1 = __builtin_amdgcn_mfma_f32_32x32x16_bf16(vf2, b0.v, o1, 0, 0, 0);
        o0 = __builtin_amdgcn_mfma_f32_32x32x16_bf16(vf1, b1.v, o0, 0, 0, 0);
        o1 = __builtin_amdgcn_mfma_f32_32x32x16_bf16(vf3, b1.v, o1, 0, 0, 0);
        __builtin_amdgcn_s_setprio(0);
    }
    lrun += __shfl_xor(lrun, 32);
    float inv = 1.0f / lrun;
    size_t obase = ((size_t)bidx * NSEQ + tq) * DIM + head * HD;
#pragma unroll
    for (int dt = 0; dt < 2; ++dt)
#pragma unroll
        for (int a = 0; a < 4; ++a) {
            union { bf16 h[4]; uint2 u; } pkd;
            const f32x16& ov = dt ? o1 : o0;
#pragma unroll
            for (int i = 0; i < 4; ++i) pkd.h[i] = __float2bfloat16(ov[4 * a + i] * inv);
            *(uint2*)&Ob[obase + dt * 32 + 8 * a + 4 * hi] = pkd.u;
        }
}

// ---------------------------------------------------------------- launch
extern "C" void kernel_launch(void* const* d_in, const int* in_sizes, int n_in,
                              void* d_out, int out_size, void* d_ws, size_t ws_size,
                              hipStream_t stream) {
    const float* x   = (const float*)d_in[0];
    const float* Wq  = (const float*)d_in[1];
    const float* Wkv = (const float*)d_in[2];
    const float* Wo  = (const float*)d_in[3];
    const float* bo  = (const float*)d_in[4];
    const float* Wo0 = (const float*)d_in[5];
    const float* bo0 = (const float*)d_in[6];
    float* out = (float*)d_out;

    char* ws = (char*)d_ws;
    size_t off = 0;
    auto alloc = [&](size_t bytes) { void* p = ws + off; off += (bytes + 255) & ~(size_t)255; return p; };
    float* cosT = (float*)alloc((size_t)NSEQ * 32 * 4);
    float* sinT = (float*)alloc((size_t)NSEQ * 32 * 4);
    bf16* Xb    = (bf16*)alloc((size_t)ROWS * DIM * 2);
    bf16* WqT   = (bf16*)alloc((size_t)DIM * DIM * 2);
    bf16* WkvT  = (bf16*)alloc((size_t)DIM * DIM * 2);
    bf16* WoT   = (bf16*)alloc((size_t)DIM * DIM * 2);
    bf16* Wo0T  = (bf16*)alloc((size_t)DIM * DIM * 2);
    bf16* Qb    = (bf16*)alloc((size_t)NC * NSEQ * HD * 2);
    bf16* KVf   = (bf16*)alloc((size_t)NC * 128 * 4096 * 2);
    bf16* Ob    = (bf16*)alloc((size_t)ROWS * DIM * 2);

    hipLaunchKernelGGL(k_rope_tab, dim3(NSEQ * 32 / 256), dim3(256), 0, stream, cosT, sinT);
    hipLaunchKernelGGL(k_convert_x, dim3(ROWS * DIM / 4 / 256), dim3(256), 0, stream, x, Xb);
    hipLaunchKernelGGL(k_transpose, dim3(32, 32), dim3(32, 8), 0, stream, Wq, WqT);
    hipLaunchKernelGGL(k_transpose, dim3(32, 32), dim3(32, 8), 0, stream, Wkv, WkvT);
    hipLaunchKernelGGL(k_transpose, dim3(32, 32), dim3(32, 8), 0, stream, Wo, WoT);
    hipLaunchKernelGGL(k_transpose, dim3(32, 32), dim3(32, 8), 0, stream, Wo0, Wo0T);

    hipLaunchKernelGGL(k_gemm_qkv, dim3(1024), dim3(256), 0, stream, Xb, WqT, WkvT, cosT, sinT, Qb, KVf);

    hipLaunchKernelGGL(k_attn, dim3(1024), dim3(256), 0, stream, Qb, KVf, Ob);

    hipLaunchKernelGGL(k_gemm_out, dim3(1024), dim3(256), 0, stream, Ob, Wo0T, WoT, bo0, bo, out);
}

// Round 12
// 154.468 us; speedup vs baseline: 2.3256x; 1.0245x over previous
//
#include <hip/hip_runtime.h>
#include <hip/hip_bf16.h>
#include <float.h>

using bf16 = __hip_bfloat16;
typedef __attribute__((ext_vector_type(8))) short bf16x8;
typedef __attribute__((ext_vector_type(4))) float f32x4;
typedef __attribute__((ext_vector_type(16))) float f32x16;

#define DIM   1024
#define NSEQ  4096
#define BATCH 2
#define NH    16
#define HD    64
#define NSEG  8
#define MSEG  512
#define ROWS  (BATCH*NSEQ)   // 8192
#define NC    (BATCH*NH)     // 32
#define QSCALE (0.125f * 1.44269504f)   // d^-0.5 * log2(e)  (exp2 softmax)

__device__ __forceinline__ float fast_exp2(float x) {
    float r;
    asm volatile("v_exp_f32 %0, %1" : "=v"(r) : "v"(x));
    return r;
}

__device__ __forceinline__ void gload16(const bf16* g, bf16* l) {
    __builtin_amdgcn_global_load_lds((const __attribute__((address_space(1))) unsigned int*)g,
                                     (__attribute__((address_space(3))) unsigned int*)l, 16, 0, 0);
}

// ---------------------------------------------------------------- rope table
__global__ void k_rope_tab(float* __restrict__ cosT, float* __restrict__ sinT) {
    int idx = blockIdx.x * 256 + threadIdx.x;     // 4096*32 = 131072
    int t = idx >> 5, i = idx & 31;
    float freq = 1.0f / powf(10000.0f, (float)(2 * i) * (1.0f / 64.0f));
    float a = (float)t * freq;
    cosT[idx] = cosf(a);
    sinT[idx] = sinf(a);
}

// ---------------------------------------------------------------- x -> bf16
__global__ void k_convert_x(const float* __restrict__ X, bf16* __restrict__ Xb) {
    int i = (blockIdx.x * 256 + threadIdx.x) * 4;
    float4 v = *(const float4*)&X[i];
    union { bf16 h[4]; uint2 u; } p;
    p.h[0] = __float2bfloat16(v.x);
    p.h[1] = __float2bfloat16(v.y);
    p.h[2] = __float2bfloat16(v.z);
    p.h[3] = __float2bfloat16(v.w);
    *(uint2*)&Xb[i] = p.u;
}

// ------------------------------------------- W[k][n] -> Wt[n][k] (bf16)
__global__ void k_transpose(const float* __restrict__ W, bf16* __restrict__ Wt) {
    __shared__ float tile[32][33];
    int bx = blockIdx.x * 32;   // n
    int by = blockIdx.y * 32;   // k
    int tx = threadIdx.x;
    for (int i = threadIdx.y; i < 32; i += 8)
        tile[i][tx] = W[(size_t)(by + i) * DIM + bx + tx];
    __syncthreads();
    for (int i = threadIdx.y; i < 32; i += 8)
        Wt[(size_t)(bx + i) * DIM + by + tx] = __float2bfloat16(tile[tx][i]);
}

// --------------- merged Q+KV projection GEMM, 3-buffer counted-vmcnt pipeline,
// FUSED RoPE epilogue (Q: coalesced Qb; KV: direct KVf fragment emission)
__launch_bounds__(256, 3)
__global__ void k_gemm_qkv(const bf16* __restrict__ A, const bf16* __restrict__ Bq,
                           const bf16* __restrict__ Bkv, const float* __restrict__ cosT,
                           const float* __restrict__ sinT, bf16* __restrict__ Qb,
                           bf16* __restrict__ KVf) {
    __shared__ alignas(16) bf16 SH[24576];        // 48KB: As 3x4096 | Bs 3x4096; bounce aliases
    bf16* AsB = SH;                               // [3][4096]
    bf16* BsB = SH + 12288;                       // [3][4096]
    const int K = DIM;
    int tid = threadIdx.x;
    int lane = tid & 63, wave = tid >> 6;
    int hi = lane >> 5, lq = lane & 31;
    int wr = (wave >> 1) * 64, wc = (wave & 1) * 64;
    int id = blockIdx.x;
    int xcd = id & 7, rank = id >> 3;      // rank 0..127
    int by = xcd * 8 + (rank >> 4);        // 0..63
    int bxx = rank & 15;                   // 0..15 (virtual n block)
    int m0 = by * 128;
    bool isQ = (bxx < 8);
    const bf16* Bt = isQ ? Bq : Bkv;
    int n0 = (bxx & 7) * 128;
    int row = lane & 15, kk = (lane >> 4) * 8;
    int ch0 = wave * 128 + lane, ch1 = ch0 + 64;
    int r0 = ch0 >> 2, c0e = (ch0 & 3) * 8;
    int r1 = ch1 >> 2, c1e = (ch1 & 3) * 8;
    f32x4 acc[4][4] = {};

    auto stage = [&](int k0, int b) {
        gload16(&A[(size_t)(m0 + r0) * K + k0 + c0e], &AsB[b * 4096 + wave * 1024]);
        gload16(&A[(size_t)(m0 + r1) * K + k0 + c1e], &AsB[b * 4096 + wave * 1024 + 512]);
        gload16(&Bt[(size_t)(n0 + r0) * K + k0 + c0e], &BsB[b * 4096 + wave * 1024]);
        gload16(&Bt[(size_t)(n0 + r1) * K + k0 + c1e], &BsB[b * 4096 + wave * 1024 + 512]);
    };
    // prologue: tiles 0 and 1 in flight; wait for tile 0 only
    stage(0, 0);
    stage(32, 1);
    asm volatile("s_waitcnt vmcnt(4)" ::: "memory");
    __builtin_amdgcn_s_barrier();
    __builtin_amdgcn_sched_barrier(0);
    int cur = 0;
    for (int k = 0; k < 32; ++k) {
        if (k + 2 < 32) {
            int nb = cur + 2; if (nb >= 3) nb -= 3;
            stage(k * 32 + 64, nb);
        }
        bf16x8 af[4], bfr[4];
#pragma unroll
        for (int mt = 0; mt < 4; ++mt) af[mt] = *(const bf16x8*)&AsB[cur * 4096 + (wr + mt * 16 + row) * 32 + kk];
#pragma unroll
        for (int nt = 0; nt < 4; ++nt) bfr[nt] = *(const bf16x8*)&BsB[cur * 4096 + (wc + nt * 16 + row) * 32 + kk];
#pragma unroll
        for (int mt = 0; mt < 4; ++mt)
#pragma unroll
            for (int nt = 0; nt < 4; ++nt)
                acc[mt][nt] = __builtin_amdgcn_mfma_f32_16x16x32_bf16(af[mt], bfr[nt], acc[mt][nt], 0, 0, 0);
        if (k + 1 < 32) {
            if (k + 2 < 32) asm volatile("s_waitcnt vmcnt(4)" ::: "memory");
            else            asm volatile("s_waitcnt vmcnt(0)" ::: "memory");
            __builtin_amdgcn_s_barrier();
            __builtin_amdgcn_sched_barrier(0);
        }
        cur = cur + 1; if (cur == 3) cur = 0;
    }
    __syncthreads();   // all LDS reads done before bounce region overwrites staging
    // ---- epilogue: rope into per-wave LDS bounce region (64 rows x 64 d, stride 72)
    bf16* Tw = SH + wave * (64 * 72);
    int orow = (lane >> 4) * 4, ocol = lane & 15;
    int head_g = (n0 + wc) >> 6;               // 0..15
    float sc = isQ ? QSCALE : 1.0f;
    int bidx = (m0 + wr) >> 12;
    int tbase = (m0 + wr) & (NSEQ - 1);
    int cch = bidx * NH + head_g;
#pragma unroll
    for (int mt = 0; mt < 4; ++mt) {
#pragma unroll
        for (int i = 0; i < 4; ++i) {
            int rl = mt * 16 + orow + i;
            int t = tbase + rl;
#pragma unroll
            for (int nt = 0; nt < 2; ++nt) {
                int e = nt * 16 + ocol;
                float x1 = acc[mt][nt][i], x2 = acc[mt][nt + 2][i];
                float cv = cosT[t * 32 + e], sv = sinT[t * 32 + e];
                Tw[rl * 72 + e]      = __float2bfloat16((x1 * cv - x2 * sv) * sc);
                Tw[rl * 72 + e + 32] = __float2bfloat16((x2 * cv + x1 * sv) * sc);
            }
        }
    }
    if (isQ) {
        int rsub = lane >> 3, dg = (lane & 7) * 8;
        size_t qbase = ((size_t)cch * NSEQ + tbase) * HD;
#pragma unroll
        for (int rr = 0; rr < 8; ++rr) {
            int rl = rr * 8 + rsub;
            *(uint4*)&Qb[qbase + (size_t)rl * HD + dg] = *(const uint4*)&Tw[rl * 72 + dg];
        }
    } else {
        size_t kvfbase = ((size_t)cch * 128 + (tbase >> 5)) * 4096;   // elements
#pragma unroll
        for (int st = 0; st < 2; ++st) {
            size_t tb = kvfbase + (size_t)st * 4096;
#pragma unroll
            for (int f = 0; f < 4; ++f)
                *(uint4*)&KVf[tb + f * 512 + lane * 8] =
                    *(const uint4*)&Tw[(st * 32 + lq) * 72 + f * 16 + hi * 8];
#pragma unroll
            for (int m = 0; m < 4; ++m) {
                int d0 = (m >> 1) * 32, sb = m & 1;
                union { bf16 h[8]; uint4 u; } pk;
#pragma unroll
                for (int j = 0; j < 8; ++j)
                    pk.h[j] = Tw[(st * 32 + sb * 16 + hi * 8 + j) * 72 + d0 + lq];
                *(uint4*)&KVf[tb + (size_t)(4 + m) * 512 + lane * 8] = pk.u;
            }
        }
    }
}

// final GEMM: 128x64 tile, 1024 blocks, 3-buffer counted-vmcnt pipeline, fp32 out
__launch_bounds__(256, 4)
__global__ void k_gemm_out(const bf16* __restrict__ A, const bf16* __restrict__ Bt0,
                           const bf16* __restrict__ Bt1, const float* __restrict__ bias0,
                           const float* __restrict__ bias1, float* __restrict__ C) {
    __shared__ alignas(16) bf16 As[3][128 * 32];
    __shared__ alignas(16) bf16 Bs[3][64 * 32];
    const int K = DIM;
    int tid = threadIdx.x;
    int lane = tid & 63, wave = tid >> 6;
    int wr = (wave >> 1) * 64, wc = (wave & 1) * 32;
    int id = blockIdx.x;                   // 1024 blocks
    int xcd = id & 7, rank = id >> 3;      // 0..127
    int by = xcd * 8 + (rank >> 4);        // 0..63
    int bx = rank & 15;                    // 0..15
    int m0 = by * 128, n0 = bx * 64;
    bool first = (m0 & (NSEQ - 1)) < MSEG;
    const bf16* Bt = first ? Bt0 : Bt1;
    const float* bias = first ? bias0 : bias1;
    int row = lane & 15, kk = (lane >> 4) * 8;
    int ch0 = wave * 128 + lane, ch1 = ch0 + 64;
    int r0 = ch0 >> 2, c0e = (ch0 & 3) * 8;
    int r1 = ch1 >> 2, c1e = (ch1 & 3) * 8;
    int cb = wave * 64 + lane;
    int rb = cb >> 2, cbe = (cb & 3) * 8;
    f32x4 acc[4][2] = {};

    auto stage = [&](int k0, int b) {
        gload16(&A[(size_t)(m0 + r0) * K + k0 + c0e], &As[b][wave * 1024]);
        gload16(&A[(size_t)(m0 + r1) * K + k0 + c1e], &As[b][wave * 1024 + 512]);
        gload16(&Bt[(size_t)(n0 + rb) * K + k0 + cbe], &Bs[b][wave * 512]);
    };
    stage(0, 0);
    stage(32, 1);
    asm volatile("s_waitcnt vmcnt(3)" ::: "memory");
    __builtin_amdgcn_s_barrier();
    __builtin_amdgcn_sched_barrier(0);
    int cur = 0;
    for (int k = 0; k < 32; ++k) {
        if (k + 2 < 32) {
            int nb = cur + 2; if (nb >= 3) nb -= 3;
            stage(k * 32 + 64, nb);
        }
        bf16x8 af[4], bfr[2];
#pragma unroll
        for (int mt = 0; mt < 4; ++mt) af[mt] = *(const bf16x8*)&As[cur][(wr + mt * 16 + row) * 32 + kk];
#pragma unroll
        for (int nt = 0; nt < 2; ++nt) bfr[nt] = *(const bf16x8*)&Bs[cur][(wc + nt * 16 + row) * 32 + kk];
#pragma unroll
        for (int mt = 0; mt < 4; ++mt)
#pragma unroll
            for (int nt = 0; nt < 2; ++nt)
                acc[mt][nt] = __builtin_amdgcn_mfma_f32_16x16x32_bf16(af[mt], bfr[nt], acc[mt][nt], 0, 0, 0);
        if (k + 1 < 32) {
            if (k + 2 < 32) asm volatile("s_waitcnt vmcnt(3)" ::: "memory");
            else            asm volatile("s_waitcnt vmcnt(0)" ::: "memory");
            __builtin_amdgcn_s_barrier();
            __builtin_amdgcn_sched_barrier(0);
        }
        cur = cur + 1; if (cur == 3) cur = 0;
    }
    int orow = (lane >> 4) * 4, ocol = lane & 15;
#pragma unroll
    for (int mt = 0; mt < 4; ++mt)
#pragma unroll
        for (int nt = 0; nt < 2; ++nt) {
            float bv = bias[n0 + wc + nt * 16 + ocol];
#pragma unroll
            for (int i = 0; i < 4; ++i)
                C[(size_t)(m0 + wr + mt * 16 + orow + i) * DIM + n0 + wc + nt * 16 + ocol] = acc[mt][nt][i] + bv;
        }
}

// ---------------------------------------------------------------- attention (swapped-QK 32x32)
// Software-pipelined: softmax(i) consumes scores computed LAST iteration; QK(i+1) issued
// after exp frees the score registers. (unchanged from R10)
__launch_bounds__(256, 4)
__global__ void k_attn(const bf16* __restrict__ Qb, const bf16* __restrict__ KVf,
                       bf16* __restrict__ Ob) {
    int lane = threadIdx.x & 63, wave = threadIdx.x >> 6;
    int hi = lane >> 5, lq = lane & 31;
    int id = blockIdx.x;
    int xcd = id & 7, rank = id >> 3;           // rank 0..127
    int c = xcd * 4 + (rank & 3);
    int hr = rank >> 2;                         // 0..31, heavy-first
    int bx, seg;
    if (hr < 28) { bx = 3 - hr / 7; seg = 1 + hr % 7; }
    else         { seg = 0; bx = 31 - hr; }
    int i0 = bx * 128 + wave * 32;              // q-row offset within segment
    int bidx = c >> 4, head = c & 15;
    int tq = seg * MSEG + i0 + lq;
    const bf16* qptr = &Qb[((size_t)c * NSEQ + tq) * HD + hi * 8];
    bf16x8 qf[4];
#pragma unroll
    for (int dc = 0; dc < 4; ++dc) qf[dc] = *(const bf16x8*)&qptr[dc * 16];
    f32x16 o0 = {}, o1 = {};
    float mrun = -FLT_MAX, lrun = 0.f;
    int kvbase = (seg == 0) ? 0 : (seg - 1) * MSEG;
    int cstart = (seg == 0) ? 0 : MSEG;
    int cend = cstart + i0 + 32;
    int nT = cend >> 5;                         // number of 32-kv tiles

    const bf16* fb = &KVf[((size_t)c * 128 + (kvbase >> 5)) * 4096 + lane * 8];

    // ---- prologue: s = QK(tile 0); ka = K(tile 1)
    bf16x8 ka0, ka1, ka2, ka3;
    f32x16 s;
    {
        bf16x8 k0 = *(const bf16x8*)&fb[0];
        bf16x8 k1 = *(const bf16x8*)&fb[512];
        bf16x8 k2 = *(const bf16x8*)&fb[1024];
        bf16x8 k3 = *(const bf16x8*)&fb[1536];
        if (nT > 1) {
            const bf16* p1 = fb + 4096;
            ka0 = *(const bf16x8*)&p1[0];
            ka1 = *(const bf16x8*)&p1[512];
            ka2 = *(const bf16x8*)&p1[1024];
            ka3 = *(const bf16x8*)&p1[1536];
        }
        f32x16 z = {};
        __builtin_amdgcn_s_setprio(1);
        z = __builtin_amdgcn_mfma_f32_32x32x16_bf16(k0, qf[0], z, 0, 0, 0);
        z = __builtin_amdgcn_mfma_f32_32x32x16_bf16(k1, qf[1], z, 0, 0, 0);
        z = __builtin_amdgcn_mfma_f32_32x32x16_bf16(k2, qf[2], z, 0, 0, 0);
        z = __builtin_amdgcn_mfma_f32_32x32x16_bf16(k3, qf[3], z, 0, 0, 0);
        __builtin_amdgcn_s_setprio(0);
        s = z;
    }

    for (int it = 0; it < nT; ++it) {
        int c0 = it * 32;
        const bf16* pv = fb + (size_t)it * 4096 + 2048;
        bf16x8 vf0 = *(const bf16x8*)&pv[0];
        bf16x8 vf1 = *(const bf16x8*)&pv[512];
        bf16x8 vf2 = *(const bf16x8*)&pv[1024];
        bf16x8 vf3 = *(const bf16x8*)&pv[1536];
        if (c0 + 31 >= cstart && c0 + 31 - cstart > i0) {
#pragma unroll
            for (int r = 0; r < 16; ++r) {
                int kvg = c0 + ((r & 3) + 8 * (r >> 2) + 4 * hi);
                if (kvg >= cstart && kvg - cstart > i0 + lq) s[r] = -FLT_MAX;
            }
        }
        float m8[8], m4[4];
#pragma unroll
        for (int r = 0; r < 8; ++r) m8[r] = fmaxf(s[2 * r], s[2 * r + 1]);
#pragma unroll
        for (int r = 0; r < 4; ++r) m4[r] = fmaxf(m8[2 * r], m8[2 * r + 1]);
        float vmax = fmaxf(fmaxf(m4[0], m4[1]), fmaxf(m4[2], m4[3]));
        vmax = fmaxf(vmax, __shfl_xor(vmax, 32));
        if (__any(vmax > mrun + 11.5f)) {
            float nm = fmaxf(mrun, vmax);
            float al = fast_exp2(mrun - nm);
#pragma unroll
            for (int r = 0; r < 16; ++r) { o0[r] *= al; o1[r] *= al; }
            lrun *= al;
            mrun = nm;
        }
        float p[16];
#pragma unroll
        for (int r = 0; r < 16; ++r) p[r] = fast_exp2(s[r] - mrun);   // s dead after this
        if (it + 1 < nT) {
            f32x16 z = {};
            __builtin_amdgcn_s_setprio(1);
            z = __builtin_amdgcn_mfma_f32_32x32x16_bf16(ka0, qf[0], z, 0, 0, 0);
            z = __builtin_amdgcn_mfma_f32_32x32x16_bf16(ka1, qf[1], z, 0, 0, 0);
            z = __builtin_amdgcn_mfma_f32_32x32x16_bf16(ka2, qf[2], z, 0, 0, 0);
            z = __builtin_amdgcn_mfma_f32_32x32x16_bf16(ka3, qf[3], z, 0, 0, 0);
            __builtin_amdgcn_s_setprio(0);
            s = z;
            if (it + 2 < nT) {
                const bf16* pn = fb + (size_t)(it + 2) * 4096;
                ka0 = *(const bf16x8*)&pn[0];
                ka1 = *(const bf16x8*)&pn[512];
                ka2 = *(const bf16x8*)&pn[1024];
                ka3 = *(const bf16x8*)&pn[1536];
            }
        }
        float a8[8], a4[4];
#pragma unroll
        for (int r = 0; r < 8; ++r) a8[r] = p[2 * r] + p[2 * r + 1];
#pragma unroll
        for (int r = 0; r < 4; ++r) a4[r] = a8[2 * r] + a8[2 * r + 1];
        lrun += (a4[0] + a4[1]) + (a4[2] + a4[3]);
        unsigned pk[8];
#pragma unroll
        for (int k = 0; k < 8; ++k) {
            union { bf16 h[2]; unsigned u; } cv;
            cv.h[0] = __float2bfloat16(p[2 * k]);
            cv.h[1] = __float2bfloat16(p[2 * k + 1]);
            pk[k] = cv.u;
        }
        unsigned u0 = hi ? pk[0] : pk[2];
        unsigned u1 = hi ? pk[1] : pk[3];
        unsigned u2 = hi ? pk[4] : pk[6];
        unsigned u3 = hi ? pk[5] : pk[7];
        unsigned w0 = (unsigned)__shfl_xor((int)u0, 32);
        unsigned w1 = (unsigned)__shfl_xor((int)u1, 32);
        unsigned w2 = (unsigned)__shfl_xor((int)u2, 32);
        unsigned w3 = (unsigned)__shfl_xor((int)u3, 32);
        union { unsigned u[4]; bf16x8 v; } b0, b1;
        b0.u[0] = hi ? w0 : pk[0];
        b0.u[1] = hi ? w1 : pk[1];
        b0.u[2] = hi ? pk[2] : w0;
        b0.u[3] = hi ? pk[3] : w1;
        b1.u[0] = hi ? w2 : pk[4];
        b1.u[1] = hi ? w3 : pk[5];
        b1.u[2] = hi ? pk[6] : w2;
        b1.u[3] = hi ? pk[7] : w3;
        __builtin_amdgcn_s_setprio(1);
        o0 = __builtin_amdgcn_mfma_f32_32x32x16_bf16(vf0, b0.v, o0, 0, 0, 0);
        o1 = __builtin_amdgcn_mfma_f32_32x32x16_bf16(vf2, b0.v, o1, 0, 0, 0);
        o0 = __builtin_amdgcn_mfma_f32_32x32x16_bf16(vf1, b1.v, o0, 0, 0, 0);
        o1 = __builtin_amdgcn_mfma_f32_32x32x16_bf16(vf3, b1.v, o1, 0, 0, 0);
        __builtin_amdgcn_s_setprio(0);
    }
    lrun += __shfl_xor(lrun, 32);
    float inv = 1.0f / lrun;
    size_t obase = ((size_t)bidx * NSEQ + tq) * DIM + head * HD;
#pragma unroll
    for (int dt = 0; dt < 2; ++dt)
#pragma unroll
        for (int a = 0; a < 4; ++a) {
            union { bf16 h[4]; uint2 u; } pkd;
            const f32x16& ov = dt ? o1 : o0;
#pragma unroll
            for (int i = 0; i < 4; ++i) pkd.h[i] = __float2bfloat16(ov[4 * a + i] * inv);
            *(uint2*)&Ob[obase + dt * 32 + 8 * a + 4 * hi] = pkd.u;
        }
}

// ---------------------------------------------------------------- launch
extern "C" void kernel_launch(void* const* d_in, const int* in_sizes, int n_in,
                              void* d_out, int out_size, void* d_ws, size_t ws_size,
                              hipStream_t stream) {
    const float* x   = (const float*)d_in[0];
    const float* Wq  = (const float*)d_in[1];
    const float* Wkv = (const float*)d_in[2];
    const float* Wo  = (const float*)d_in[3];
    const float* bo  = (const float*)d_in[4];
    const float* Wo0 = (const float*)d_in[5];
    const float* bo0 = (const float*)d_in[6];
    float* out = (float*)d_out;

    char* ws = (char*)d_ws;
    size_t off = 0;
    auto alloc = [&](size_t bytes) { void* p = ws + off; off += (bytes + 255) & ~(size_t)255; return p; };
    float* cosT = (float*)alloc((size_t)NSEQ * 32 * 4);
    float* sinT = (float*)alloc((size_t)NSEQ * 32 * 4);
    bf16* Xb    = (bf16*)alloc((size_t)ROWS * DIM * 2);
    bf16* WqT   = (bf16*)alloc((size_t)DIM * DIM * 2);
    bf16* WkvT  = (bf16*)alloc((size_t)DIM * DIM * 2);
    bf16* WoT   = (bf16*)alloc((size_t)DIM * DIM * 2);
    bf16* Wo0T  = (bf16*)alloc((size_t)DIM * DIM * 2);
    bf16* Qb    = (bf16*)alloc((size_t)NC * NSEQ * HD * 2);
    bf16* KVf   = (bf16*)alloc((size_t)NC * 128 * 4096 * 2);
    bf16* Ob    = (bf16*)alloc((size_t)ROWS * DIM * 2);

    hipLaunchKernelGGL(k_rope_tab, dim3(NSEQ * 32 / 256), dim3(256), 0, stream, cosT, sinT);
    hipLaunchKernelGGL(k_convert_x, dim3(ROWS * DIM / 4 / 256), dim3(256), 0, stream, x, Xb);
    hipLaunchKernelGGL(k_transpose, dim3(32, 32), dim3(32, 8), 0, stream, Wq, WqT);
    hipLaunchKernelGGL(k_transpose, dim3(32, 32), dim3(32, 8), 0, stream, Wkv, WkvT);
    hipLaunchKernelGGL(k_transpose, dim3(32, 32), dim3(32, 8), 0, stream, Wo, WoT);
    hipLaunchKernelGGL(k_transpose, dim3(32, 32), dim3(32, 8), 0, stream, Wo0, Wo0T);

    hipLaunchKernelGGL(k_gemm_qkv, dim3(1024), dim3(256), 0, stream, Xb, WqT, WkvT, cosT, sinT, Qb, KVf);

    hipLaunchKernelGGL(k_attn, dim3(1024), dim3(256), 0, stream, Qb, KVf, Ob);

    hipLaunchKernelGGL(k_gemm_out, dim3(1024), dim3(256), 0, stream, Ob, Wo0T, WoT, bo0, bo, out);
}